// Round 1
// baseline (761.533 us; speedup 1.0000x reference)
//
#include <hip/hip_runtime.h>

// Problem constants
#define BB 2
#define SS 2048
#define DD 768
#define HH 12
#define HDIM 64
#define NWORDS 8          // 512 hash bits = 8 u64
#define HAM_MAX 179       // sim > 0.3  <=>  hamming <= 179
// ws layout (bytes): needs ~73.4 MB
#define OFF_Q     ((size_t)0)
#define OFF_K     ((size_t)12582912)
#define OFF_V     ((size_t)25165824)
#define OFF_CTX   ((size_t)37748736)
#define OFF_CTX2  ((size_t)50331648)
#define OFF_PROJ  ((size_t)62914560)
#define OFF_CODES ((size_t)71303168)
#define OFF_HPW   ((size_t)71565312)

// ---------------------------------------------------------------------------
// Build permuted hash-projection weight: HPW[kk][h*64+c], kk in [0,896)
//   kk < 768 : hash_proj[h][kk][c]
//   kk >= 768: 0.1 * hash_proj[h][kk-768][c]   (topo part, TEMP folded in)
__global__ __launch_bounds__(256) void build_hpw(const float* __restrict__ hp,
                                                 float* __restrict__ hpw) {
    int idx = blockIdx.x * 256 + threadIdx.x;
    if (idx >= 896 * 512) return;
    int kk = idx >> 9, hc = idx & 511;
    int h = hc >> 6, c = hc & 63;
    float v;
    if (kk < 768) v = hp[((size_t)h * 768 + kk) * 64 + c];
    else          v = 0.1f * hp[((size_t)h * 768 + (kk - 768)) * 64 + c];
    hpw[idx] = v;
}

// ---------------------------------------------------------------------------
// Generic tiled f32 GEMM: out = concat(A[K1], A2[K2]) @ W[K1+K2, N] (+bias)
// mode 0: plain row-major store (+bias if non-null)
// mode 1: QKV scatter to [B,H,S,HD]
// mode 2: gate epilogue: g=sigmoid(acc+bias); out = g*gctx + (1-g)*ghs
__global__ __launch_bounds__(256) void gemm64(
    const float* __restrict__ A, const float* __restrict__ A2,
    const float* __restrict__ W, const float* __restrict__ bias,
    float* __restrict__ out, int N, int K1, int K2, int mode,
    const float* __restrict__ gctx, const float* __restrict__ ghs) {
    __shared__ float As[16][68];
    __shared__ float Bs[16][68];
    const int t = threadIdx.x;
    const int tx = t & 15, ty = t >> 4;
    const int row0 = blockIdx.y << 6, col0 = blockIdx.x << 6;
    const int K = K1 + K2;
    float acc[4][4] = {};
    const int m = t >> 2, kq = (t & 3) << 2;   // A-tile load coords
    const int kw = t >> 4, n4 = (t & 15) << 2; // W-tile load coords

    for (int k0 = 0; k0 < K; k0 += 16) {
        int kk0 = k0 + kq;
        float4 a4;
        if (kk0 < K1) a4 = *(const float4*)(A + (size_t)(row0 + m) * K1 + kk0);
        else          a4 = *(const float4*)(A2 + (size_t)(row0 + m) * K2 + (kk0 - K1));
        float4 w4 = *(const float4*)(W + (size_t)(k0 + kw) * N + col0 + n4);
        As[kq + 0][m] = a4.x; As[kq + 1][m] = a4.y;
        As[kq + 2][m] = a4.z; As[kq + 3][m] = a4.w;
        *(float4*)&Bs[kw][n4] = w4;
        __syncthreads();
#pragma unroll
        for (int kk = 0; kk < 16; ++kk) {
            float4 av = *(const float4*)&As[kk][ty << 2];
            float4 bv = *(const float4*)&Bs[kk][tx << 2];
            float a[4] = {av.x, av.y, av.z, av.w};
            float b[4] = {bv.x, bv.y, bv.z, bv.w};
#pragma unroll
            for (int i = 0; i < 4; ++i)
#pragma unroll
                for (int j = 0; j < 4; ++j)
                    acc[i][j] = fmaf(a[i], b[j], acc[i][j]);
        }
        __syncthreads();
    }
#pragma unroll
    for (int i = 0; i < 4; ++i) {
        int row = row0 + (ty << 2) + i;
#pragma unroll
        for (int j = 0; j < 4; ++j) {
            int col = col0 + (tx << 2) + j;
            float c = acc[i][j];
            if (mode == 0) {
                if (bias) c += bias[col];
                out[(size_t)row * N + col] = c;
            } else if (mode == 1) {
                int bidx = row >> 11, s = row & 2047;
                int h = col >> 6, hd = col & 63;
                out[(((size_t)bidx * HH + h) * SS + s) * HDIM + hd] = c;
            } else {
                c += bias[col];
                float g = 1.f / (1.f + __expf(-c));
                size_t off = (size_t)row * N + col;
                out[off] = g * gctx[off] + (1.f - g) * ghs[off];
            }
        }
    }
}

// ---------------------------------------------------------------------------
// Pack sign bits of proj[4096][512] into codes[4096][8] u64 via wave ballot
__global__ __launch_bounds__(512) void pack_codes(const float* __restrict__ proj,
                                                  unsigned long long* __restrict__ codes) {
    int row = blockIdx.x, t = threadIdx.x;
    float v = proj[(size_t)row * 512 + t];
    unsigned long long bal = __ballot(v > 0.f);
    if ((t & 63) == 0) codes[(size_t)row * NWORDS + (t >> 6)] = bal;
}

// ---------------------------------------------------------------------------
// Fused LSH attention, flash-style with exact chunk skipping.
// Block: 256 threads; 64 query rows, 4 lanes per row (tx = col/dim quarter).
__global__ __launch_bounds__(256) void attn_kernel(
    const float* __restrict__ qm, const float* __restrict__ km,
    const float* __restrict__ vm, const unsigned long long* __restrict__ codes,
    const int* __restrict__ mask, float* __restrict__ ctx) {
    __shared__ float Qs[64][68], Ks[64][68], Vs[64][68];
    __shared__ unsigned long long ckS[64][NWORDS];
    __shared__ int mskS[64];
    __shared__ int anyflag;
    const int t = threadIdx.x;
    const int r = t >> 2, tx = t & 3;
    const int q0 = blockIdx.x << 6;
    const int bh = blockIdx.y;
    const int b = bh / HH, h = bh % HH;

    // Q tile -> LDS
    const float* qbase = qm + ((size_t)bh * SS + q0) * HDIM;
#pragma unroll
    for (int i = 0; i < 4; ++i) {
        int idx = t + (i << 8);
        int rr = idx >> 4, c4 = (idx & 15) << 2;
        *(float4*)&Qs[rr][c4] = *(const float4*)(qbase + rr * HDIM + c4);
    }
    // this row's codes -> regs
    unsigned long long cq[NWORDS];
    {
        const unsigned long long* cp = codes + ((size_t)b * SS + q0 + r) * NWORDS;
#pragma unroll
        for (int w = 0; w < NWORDS; ++w) cq[w] = cp[w];
    }
    float mrun = -1e30f, lrun = 0.f;
    float acc[16];
#pragma unroll
    for (int i = 0; i < 16; ++i) acc[i] = 0.f;

    const float* kbase0 = km + (size_t)bh * SS * HDIM;
    const float* vbase0 = vm + (size_t)bh * SS * HDIM;

    for (int k0 = 0; k0 < SS; k0 += 64) {
        __syncthreads();                 // fence prev compute / flag reuse
        if (t == 0) anyflag = 0;
#pragma unroll
        for (int i = 0; i < 2; ++i) {
            int wi = t + (i << 8);
            int jr = wi >> 3, ww = wi & 7;
            ckS[jr][ww] = codes[((size_t)b * SS + k0 + jr) * NWORDS + ww];
        }
        if (t < 64) mskS[t] = mask[b * SS + k0 + t];
        __syncthreads();
        // keep mask for this thread's 16 key columns
        unsigned int keep16 = 0;
#pragma unroll
        for (int j16 = 0; j16 < 16; ++j16) {
            int j = (tx << 4) + j16;
            int ham = 0;
#pragma unroll
            for (int w = 0; w < NWORDS; ++w)
                ham += __popcll(cq[w] ^ ckS[j][w]);
            if (ham <= HAM_MAX && mskS[j]) keep16 |= (1u << j16);
        }
        if (keep16) atomicOr(&anyflag, 1);
        __syncthreads();
        if (anyflag == 0) continue;      // exact: dropped keys give exp()==0

        // load K, V tiles (only for active chunks)
        const float* kb = kbase0 + (size_t)k0 * HDIM;
        const float* vb = vbase0 + (size_t)k0 * HDIM;
#pragma unroll
        for (int i = 0; i < 4; ++i) {
            int idx = t + (i << 8);
            int rr = idx >> 4, c4 = (idx & 15) << 2;
            *(float4*)&Ks[rr][c4] = *(const float4*)(kb + rr * HDIM + c4);
            *(float4*)&Vs[rr][c4] = *(const float4*)(vb + rr * HDIM + c4);
        }
        __syncthreads();

        // scores: this thread's 16 key cols x 64 dims
        float p[16];
#pragma unroll
        for (int j16 = 0; j16 < 16; ++j16) p[j16] = 0.f;
        for (int d4 = 0; d4 < 64; d4 += 4) {
            float4 q4 = *(const float4*)&Qs[r][d4];
#pragma unroll
            for (int j16 = 0; j16 < 16; ++j16) {
                float4 k4 = *(const float4*)&Ks[(tx << 4) + j16][d4];
                p[j16] += q4.x * k4.x + q4.y * k4.y + q4.z * k4.z + q4.w * k4.w;
            }
        }
        float mloc = -1e30f;
#pragma unroll
        for (int j16 = 0; j16 < 16; ++j16) {
            float sv = (keep16 >> j16 & 1) ? p[j16] * 0.125f : -1e30f;
            p[j16] = sv;
            mloc = fmaxf(mloc, sv);
        }
        mloc = fmaxf(mloc, __shfl_xor(mloc, 1, 4));
        mloc = fmaxf(mloc, __shfl_xor(mloc, 2, 4));
        float mnew = fmaxf(mrun, mloc);
        float psum = 0.f;
#pragma unroll
        for (int j16 = 0; j16 < 16; ++j16) {
            float pe = (keep16 >> j16 & 1) ? __expf(p[j16] - mnew) : 0.f;
            p[j16] = pe;
            psum += pe;
        }
        psum += __shfl_xor(psum, 1, 4);
        psum += __shfl_xor(psum, 2, 4);
        float scale = __expf(mrun - mnew);
        lrun = lrun * scale + psum;
#pragma unroll
        for (int i = 0; i < 16; ++i) acc[i] *= scale;
        mrun = mnew;
        // PV: broadcast p across the 4 row-lanes via shfl, accumulate 16 dims
#pragma unroll
        for (int j = 0; j < 64; ++j) {
            float pj = __shfl(p[j & 15], j >> 4, 4);
#pragma unroll
            for (int i4 = 0; i4 < 4; ++i4) {
                float4 v4 = *(const float4*)&Vs[j][(tx << 4) + (i4 << 2)];
                acc[i4 * 4 + 0] = fmaf(pj, v4.x, acc[i4 * 4 + 0]);
                acc[i4 * 4 + 1] = fmaf(pj, v4.y, acc[i4 * 4 + 1]);
                acc[i4 * 4 + 2] = fmaf(pj, v4.z, acc[i4 * 4 + 2]);
                acc[i4 * 4 + 3] = fmaf(pj, v4.w, acc[i4 * 4 + 3]);
            }
        }
    }
    float invl = lrun > 0.f ? 1.f / lrun : 0.f;
    float* cb = ctx + ((size_t)b * SS + q0 + r) * DD + h * HDIM + (tx << 4);
#pragma unroll
    for (int i = 0; i < 16; ++i) cb[i] = acc[i] * invl;
}

// ---------------------------------------------------------------------------
extern "C" void kernel_launch(void* const* d_in, const int* in_sizes, int n_in,
                              void* d_out, int out_size, void* d_ws, size_t ws_size,
                              hipStream_t stream) {
    const float* hs = (const float*)d_in[0];
    const float* tf = (const float*)d_in[1];
    const float* Wq = (const float*)d_in[2];
    const float* Wk = (const float*)d_in[3];
    const float* Wv = (const float*)d_in[4];
    const float* Wo = (const float*)d_in[5];
    const float* bo = (const float*)d_in[6];
    const float* Wg = (const float*)d_in[7];
    const float* bg = (const float*)d_in[8];
    const float* hp = (const float*)d_in[9];
    const float* tb = (const float*)d_in[10];
    const int* msk  = (const int*)d_in[11];
    float* out = (float*)d_out;

    char* w = (char*)d_ws;
    float* q    = (float*)(w + OFF_Q);
    float* k    = (float*)(w + OFF_K);
    float* v    = (float*)(w + OFF_V);
    float* ctx  = (float*)(w + OFF_CTX);
    float* ctx2 = (float*)(w + OFF_CTX2);
    float* proj = (float*)(w + OFF_PROJ);
    unsigned long long* codes = (unsigned long long*)(w + OFF_CODES);
    float* hpw  = (float*)(w + OFF_HPW);

    dim3 g12(12, 64), g8(8, 64);
    build_hpw<<<dim3((896 * 512 + 255) / 256), 256, 0, stream>>>(hp, hpw);
    // QKV projections, scattered to [B,H,S,HD]
    gemm64<<<g12, 256, 0, stream>>>(hs, nullptr, Wq, nullptr, q, 768, 768, 0, 1, nullptr, nullptr);
    gemm64<<<g12, 256, 0, stream>>>(hs, nullptr, Wk, nullptr, k, 768, 768, 0, 1, nullptr, nullptr);
    gemm64<<<g12, 256, 0, stream>>>(hs, nullptr, Wv, nullptr, v, 768, 768, 0, 1, nullptr, nullptr);
    // LSH projection (hs*HP + 0.1*tf*HP_topo + bias) as one GEMM
    gemm64<<<g8, 256, 0, stream>>>(hs, tf, hpw, tb, proj, 512, 768, 128, 0, nullptr, nullptr);
    pack_codes<<<4096, 512, 0, stream>>>(proj, codes);
    // fused LSH-masked flash attention
    attn_kernel<<<dim3(32, 24), 256, 0, stream>>>(q, k, v, codes, msk, ctx);
    // gate: sigmoid([ctx, tf] @ Wg + bg); ctx2 = g*ctx + (1-g)*hs
    gemm64<<<g12, 256, 0, stream>>>(ctx, tf, Wg, bg, ctx2, 768, 768, 128, 2, ctx, hs);
    // output projection
    gemm64<<<g12, 256, 0, stream>>>(ctx2, nullptr, Wo, bo, out, 768, 768, 0, 0, nullptr, nullptr);
}

// Round 2
// 598.055 us; speedup vs baseline: 1.2734x; 1.2734x over previous
//
#include <hip/hip_runtime.h>

// Problem constants
#define BB 2
#define SS 2048
#define DD 768
#define HH 12
#define HDIM 64
#define NWORDS 8          // 512 hash bits = 8 u64
#define HAM_MAX 179       // sim > 0.3  <=>  hamming <= 179
// ws layout (bytes)
#define OFF_Q     ((size_t)0)
#define OFF_K     ((size_t)12582912)
#define OFF_V     ((size_t)25165824)
#define OFF_CTX   ((size_t)37748736)
#define OFF_CTX2  ((size_t)50331648)
#define OFF_PROJ  ((size_t)62914560)
#define OFF_CODES ((size_t)71303168)
#define OFF_HPW   ((size_t)71565312)
// keepArr / chunkmask overlay the proj buffer (dead after pack_codes)
#define OFF_KEEP  OFF_PROJ
#define OFF_CMASK (OFF_PROJ + (size_t)1048576)

// ---------------------------------------------------------------------------
// Build permuted hash-projection weight: HPW[kk][h*64+c], kk in [0,896)
__global__ __launch_bounds__(256) void build_hpw(const float* __restrict__ hp,
                                                 float* __restrict__ hpw) {
    int idx = blockIdx.x * 256 + threadIdx.x;
    if (idx >= 896 * 512) return;
    int kk = idx >> 9, hc = idx & 511;
    int h = hc >> 6, c = hc & 63;
    float v;
    if (kk < 768) v = hp[((size_t)h * 768 + kk) * 64 + c];
    else          v = 0.1f * hp[((size_t)h * 768 + (kk - 768)) * 64 + c];
    hpw[idx] = v;
}

// ---------------------------------------------------------------------------
// Generic tiled f32 GEMM: out = concat(A[K1], A2[K2]) @ W[K1+K2, N] (+bias)
__global__ __launch_bounds__(256) void gemm64(
    const float* __restrict__ A, const float* __restrict__ A2,
    const float* __restrict__ W, const float* __restrict__ bias,
    float* __restrict__ out, int N, int K1, int K2, int mode,
    const float* __restrict__ gctx, const float* __restrict__ ghs) {
    __shared__ float As[16][68];
    __shared__ float Bs[16][68];
    const int t = threadIdx.x;
    const int tx = t & 15, ty = t >> 4;
    const int row0 = blockIdx.y << 6, col0 = blockIdx.x << 6;
    const int K = K1 + K2;
    float acc[4][4] = {};
    const int m = t >> 2, kq = (t & 3) << 2;   // A-tile load coords
    const int kw = t >> 4, n4 = (t & 15) << 2; // W-tile load coords

    for (int k0 = 0; k0 < K; k0 += 16) {
        int kk0 = k0 + kq;
        float4 a4;
        if (kk0 < K1) a4 = *(const float4*)(A + (size_t)(row0 + m) * K1 + kk0);
        else          a4 = *(const float4*)(A2 + (size_t)(row0 + m) * K2 + (kk0 - K1));
        float4 w4 = *(const float4*)(W + (size_t)(k0 + kw) * N + col0 + n4);
        As[kq + 0][m] = a4.x; As[kq + 1][m] = a4.y;
        As[kq + 2][m] = a4.z; As[kq + 3][m] = a4.w;
        *(float4*)&Bs[kw][n4] = w4;
        __syncthreads();
#pragma unroll
        for (int kk = 0; kk < 16; ++kk) {
            float4 av = *(const float4*)&As[kk][ty << 2];
            float4 bv = *(const float4*)&Bs[kk][tx << 2];
            float a[4] = {av.x, av.y, av.z, av.w};
            float b[4] = {bv.x, bv.y, bv.z, bv.w};
#pragma unroll
            for (int i = 0; i < 4; ++i)
#pragma unroll
                for (int j = 0; j < 4; ++j)
                    acc[i][j] = fmaf(a[i], b[j], acc[i][j]);
        }
        __syncthreads();
    }
#pragma unroll
    for (int i = 0; i < 4; ++i) {
        int row = row0 + (ty << 2) + i;
#pragma unroll
        for (int j = 0; j < 4; ++j) {
            int col = col0 + (tx << 2) + j;
            float c = acc[i][j];
            if (mode == 0) {
                if (bias) c += bias[col];
                out[(size_t)row * N + col] = c;
            } else if (mode == 1) {
                int bidx = row >> 11, s = row & 2047;
                int h = col >> 6, hd = col & 63;
                out[(((size_t)bidx * HH + h) * SS + s) * HDIM + hd] = c;
            } else {
                c += bias[col];
                float g = 1.f / (1.f + __expf(-c));
                size_t off = (size_t)row * N + col;
                out[off] = g * gctx[off] + (1.f - g) * ghs[off];
            }
        }
    }
}

// ---------------------------------------------------------------------------
// Pack sign bits of proj[4096][512] into codes[4096][8] u64 via wave ballot
__global__ __launch_bounds__(512) void pack_codes(const float* __restrict__ proj,
                                                  unsigned long long* __restrict__ codes) {
    int row = blockIdx.x, t = threadIdx.x;
    float v = proj[(size_t)row * 512 + t];
    unsigned long long bal = __ballot(v > 0.f);
    if ((t & 63) == 0) codes[(size_t)row * NWORDS + (t >> 6)] = bal;
}

// ---------------------------------------------------------------------------
// Precompute LSH keep masks ONCE per batch (not per head).
// Grid (32 qchunks, 2 b), 512 threads: 64 q-rows x 8 lanes (8 keys each).
// Outputs: keepArr[b*2048+row][kchunk] u64 bitmask of kept keys;
//          chunkmask[b*32+qchunk] u32 bitmap of active k-chunks.
__global__ __launch_bounds__(512) void mask_kernel(
    const unsigned long long* __restrict__ codes, const int* __restrict__ mask,
    unsigned long long* __restrict__ keepArr, unsigned int* __restrict__ chunkmask) {
    __shared__ unsigned long long ckS[64][NWORDS];
    __shared__ int mskS[64];
    __shared__ unsigned int cmaskS;
    const int t = threadIdx.x;
    const int r = t >> 3, tx = t & 7;
    const int q0 = blockIdx.x << 6, b = blockIdx.y;

    unsigned long long cq[NWORDS];
    {
        const unsigned long long* cp = codes + ((size_t)(b * SS + q0 + r)) * NWORDS;
#pragma unroll
        for (int w = 0; w < NWORDS; ++w) cq[w] = cp[w];
    }
    if (t == 0) cmaskS = 0u;

    for (int kc = 0; kc < 32; ++kc) {
        __syncthreads();   // protect ckS reuse
        {   // stage 64 key codes, XOR-swizzled on word slot: slot = w ^ (row>>3)
            int jr = t >> 3, ww = t & 7;
            ckS[jr][ww ^ (jr >> 3)] =
                codes[((size_t)(b * SS + (kc << 6) + jr)) * NWORDS + ww];
        }
        if (t < 64) mskS[t] = mask[b * SS + (kc << 6) + t];
        __syncthreads();

        unsigned int keep8 = 0;
#pragma unroll
        for (int j8 = 0; j8 < 8; ++j8) {
            int j = (tx << 3) + j8;
            int ham = 0;
#pragma unroll
            for (int w = 0; w < NWORDS; ++w)
                ham += __popcll(cq[w] ^ ckS[j][w ^ tx]);
            if (ham <= HAM_MAX && mskS[j]) keep8 |= (1u << j8);
        }
        // gather the 8 lanes' keep8 into one u64 per row
        unsigned long long k64 = 0;
#pragma unroll
        for (int i = 0; i < 8; ++i)
            k64 |= ((unsigned long long)(__shfl(keep8, i, 8) & 0xFFu)) << (8 * i);
        if (tx == 0) keepArr[((size_t)(b * SS + q0 + r)) * 32 + kc] = k64;
        if (keep8) atomicOr(&cmaskS, 1u << kc);
    }
    __syncthreads();
    if (t == 0) chunkmask[b * 32 + blockIdx.x] = cmaskS;
}

// ---------------------------------------------------------------------------
// Fused LSH attention v2: iterate ONLY active chunks via precomputed bitmap.
// Block 256: 64 query rows, 4 lanes per row.
__global__ __launch_bounds__(256) void attn_kernel(
    const float* __restrict__ qm, const float* __restrict__ km,
    const float* __restrict__ vm, const unsigned long long* __restrict__ keepArr,
    const unsigned int* __restrict__ chunkmask, float* __restrict__ ctx) {
    __shared__ float Qs[64][68], Ks[64][68], Vs[64][68];
    const int t = threadIdx.x;
    const int r = t >> 2, tx = t & 3;
    const int q0 = blockIdx.x << 6;
    const int bh = blockIdx.y;
    const int b = bh / HH, h = bh % HH;

    // Q tile -> LDS (linear)
    const float* qbase = qm + ((size_t)bh * SS + q0) * HDIM;
#pragma unroll
    for (int i = 0; i < 4; ++i) {
        int idx = t + (i << 8);
        int rr = idx >> 4, c4 = (idx & 15) << 2;
        *(float4*)&Qs[rr][c4] = *(const float4*)(qbase + rr * HDIM + c4);
    }
    unsigned int cm = chunkmask[b * 32 + blockIdx.x];
    const size_t rowIdx = (size_t)(b * SS + q0 + r);

    float mrun = -1e30f, lrun = 0.f;
    float acc[16];
#pragma unroll
    for (int i = 0; i < 16; ++i) acc[i] = 0.f;

    const float* kbase0 = km + (size_t)bh * SS * HDIM;
    const float* vbase0 = vm + (size_t)bh * SS * HDIM;

    while (cm) {
        int kc = __ffs(cm) - 1;
        cm &= cm - 1;
        unsigned long long k64 = keepArr[rowIdx * 32 + kc];
        unsigned int keep16 = (unsigned int)(k64 >> (tx << 4)) & 0xFFFFu;

        __syncthreads();   // fences Q staging (1st iter) / prior Vs reads
        // stage K (column-XOR-swizzled) and V (linear)
        const float* kb = kbase0 + ((size_t)kc << 6) * HDIM;
        const float* vb = vbase0 + ((size_t)kc << 6) * HDIM;
#pragma unroll
        for (int i = 0; i < 4; ++i) {
            int idx = t + (i << 8);
            int rr = idx >> 4, c4 = (idx & 15) << 2;
            *(float4*)&Ks[rr][c4 ^ ((rr >> 4) << 2)] = *(const float4*)(kb + rr * HDIM + c4);
            *(float4*)&Vs[rr][c4] = *(const float4*)(vb + rr * HDIM + c4);
        }
        __syncthreads();

        // scores: this thread's 16 key cols x 64 dims
        float p[16];
#pragma unroll
        for (int j16 = 0; j16 < 16; ++j16) p[j16] = 0.f;
        for (int d4 = 0; d4 < 64; d4 += 4) {
            float4 q4 = *(const float4*)&Qs[r][d4];
#pragma unroll
            for (int j16 = 0; j16 < 16; ++j16) {
                float4 k4 = *(const float4*)&Ks[(tx << 4) + j16][d4 ^ (tx << 2)];
                p[j16] += q4.x * k4.x + q4.y * k4.y + q4.z * k4.z + q4.w * k4.w;
            }
        }
        float mloc = -1e30f;
#pragma unroll
        for (int j16 = 0; j16 < 16; ++j16) {
            float sv = (keep16 >> j16 & 1) ? p[j16] * 0.125f : -1e30f;
            p[j16] = sv;
            mloc = fmaxf(mloc, sv);
        }
        mloc = fmaxf(mloc, __shfl_xor(mloc, 1, 4));
        mloc = fmaxf(mloc, __shfl_xor(mloc, 2, 4));
        float mnew = fmaxf(mrun, mloc);
        float psum = 0.f;
#pragma unroll
        for (int j16 = 0; j16 < 16; ++j16) {
            float pe = (keep16 >> j16 & 1) ? __expf(p[j16] - mnew) : 0.f;
            p[j16] = pe;
            psum += pe;
        }
        psum += __shfl_xor(psum, 1, 4);
        psum += __shfl_xor(psum, 2, 4);
        float scale = __expf(mrun - mnew);
        lrun = lrun * scale + psum;
#pragma unroll
        for (int i = 0; i < 16; ++i) acc[i] *= scale;
        mrun = mnew;
        // PV: broadcast p across the 4 row-lanes via shfl
#pragma unroll
        for (int j = 0; j < 64; ++j) {
            float pj = __shfl(p[j & 15], j >> 4, 4);
#pragma unroll
            for (int i4 = 0; i4 < 4; ++i4) {
                float4 v4 = *(const float4*)&Vs[j][(tx << 4) + (i4 << 2)];
                acc[i4 * 4 + 0] = fmaf(pj, v4.x, acc[i4 * 4 + 0]);
                acc[i4 * 4 + 1] = fmaf(pj, v4.y, acc[i4 * 4 + 1]);
                acc[i4 * 4 + 2] = fmaf(pj, v4.z, acc[i4 * 4 + 2]);
                acc[i4 * 4 + 3] = fmaf(pj, v4.w, acc[i4 * 4 + 3]);
            }
        }
    }
    float invl = lrun > 0.f ? 1.f / lrun : 0.f;
    float* cb = ctx + ((size_t)b * SS + q0 + r) * DD + h * HDIM + (tx << 4);
#pragma unroll
    for (int i = 0; i < 16; ++i) cb[i] = acc[i] * invl;
}

// ---------------------------------------------------------------------------
extern "C" void kernel_launch(void* const* d_in, const int* in_sizes, int n_in,
                              void* d_out, int out_size, void* d_ws, size_t ws_size,
                              hipStream_t stream) {
    const float* hs = (const float*)d_in[0];
    const float* tf = (const float*)d_in[1];
    const float* Wq = (const float*)d_in[2];
    const float* Wk = (const float*)d_in[3];
    const float* Wv = (const float*)d_in[4];
    const float* Wo = (const float*)d_in[5];
    const float* bo = (const float*)d_in[6];
    const float* Wg = (const float*)d_in[7];
    const float* bg = (const float*)d_in[8];
    const float* hp = (const float*)d_in[9];
    const float* tb = (const float*)d_in[10];
    const int* msk  = (const int*)d_in[11];
    float* out = (float*)d_out;

    char* w = (char*)d_ws;
    float* q    = (float*)(w + OFF_Q);
    float* k    = (float*)(w + OFF_K);
    float* v    = (float*)(w + OFF_V);
    float* ctx  = (float*)(w + OFF_CTX);
    float* ctx2 = (float*)(w + OFF_CTX2);
    float* proj = (float*)(w + OFF_PROJ);
    unsigned long long* codes = (unsigned long long*)(w + OFF_CODES);
    float* hpw  = (float*)(w + OFF_HPW);
    unsigned long long* keepArr = (unsigned long long*)(w + OFF_KEEP);
    unsigned int* cmask = (unsigned int*)(w + OFF_CMASK);

    dim3 g12(12, 64), g8(8, 64);
    build_hpw<<<dim3((896 * 512 + 255) / 256), 256, 0, stream>>>(hp, hpw);
    // QKV projections, scattered to [B,H,S,HD]
    gemm64<<<g12, 256, 0, stream>>>(hs, nullptr, Wq, nullptr, q, 768, 768, 0, 1, nullptr, nullptr);
    gemm64<<<g12, 256, 0, stream>>>(hs, nullptr, Wk, nullptr, k, 768, 768, 0, 1, nullptr, nullptr);
    gemm64<<<g12, 256, 0, stream>>>(hs, nullptr, Wv, nullptr, v, 768, 768, 0, 1, nullptr, nullptr);
    // LSH projection (hs*HP + 0.1*tf*HP_topo + bias) as one GEMM
    gemm64<<<g8, 256, 0, stream>>>(hs, tf, hpw, tb, proj, 512, 768, 128, 0, nullptr, nullptr);
    pack_codes<<<4096, 512, 0, stream>>>(proj, codes);
    // precompute keep masks once per batch (proj buffer is dead now; reuse it)
    mask_kernel<<<dim3(32, 2), 512, 0, stream>>>(codes, msk, keepArr, cmask);
    // fused LSH-masked flash attention over active chunks only
    attn_kernel<<<dim3(32, 24), 256, 0, stream>>>(q, k, v, keepArr, cmask, ctx);
    // gate: sigmoid([ctx, tf] @ Wg + bg); ctx2 = g*ctx + (1-g)*hs
    gemm64<<<g12, 256, 0, stream>>>(ctx, tf, Wg, bg, ctx2, 768, 768, 128, 2, ctx, hs);
    // output projection
    gemm64<<<g12, 256, 0, stream>>>(ctx2, nullptr, Wo, bo, out, 768, 768, 0, 0, nullptr, nullptr);
}

// Round 3
// 217.981 us; speedup vs baseline: 3.4936x; 2.7436x over previous
//
#include <hip/hip_runtime.h>

typedef __attribute__((ext_vector_type(4))) float v4f;
typedef __attribute__((ext_vector_type(8))) short v8s;

// Problem constants
#define BB 2
#define SS 2048
#define DD 768
#define HH 12
#define HDIM 64
#define NWORDS 8          // 512 hash bits = 8 u64
#define HAM_MAX 179       // sim > 0.3  <=>  hamming <= 179

// ws layout (bytes), max use 72.94 MB (ws proven >= 73.4 MB)
#define OFF_Q      ((size_t)0)
#define OFF_K      ((size_t)12582912)
#define OFF_V      ((size_t)25165824)
#define OFF_CTX    ((size_t)37748736)   // ctx f32 (after attn); proj f32 before; WoT after gate
#define OFF_PROJ   OFF_CTX
#define OFF_WOT    OFF_CTX
#define OFF_HSBF   ((size_t)50331648)
#define OFF_TFBF   ((size_t)56623104)
#define OFF_CTXBF  ((size_t)57671680)   // ctx bf16 (attn out); WtQKV before attn
#define OFF_WTQKV  OFF_CTXBF
#define OFF_CTX2BF ((size_t)63963136)
#define OFF_CODES  ((size_t)70254592)
#define OFF_KEEP   ((size_t)70516736)   // keepArr; hpwT before mask_kernel
#define OFF_HPWT   OFF_KEEP
#define OFF_CMASK  ((size_t)71565312)
#define OFF_WGT    ((size_t)71565568)

__device__ inline short f2bf(float x) {
    unsigned u = __float_as_uint(x);
    u = (u + 0x7FFFu + ((u >> 16) & 1u)) >> 16;  // RNE
    return (short)u;
}

// ---------------------------------------------------------------------------
// Convert activations f32 -> bf16 (hs and tf in one launch)
__global__ __launch_bounds__(256) void conv_act(
    const float* __restrict__ a, int na8, const float* __restrict__ b, int nb8,
    short* __restrict__ oa, short* __restrict__ ob) {
    int i = blockIdx.x * 256 + threadIdx.x;
    if (i >= na8 + nb8) return;
    const float* src; short* dst; int off;
    if (i < na8) { src = a; dst = oa; off = i << 3; }
    else         { src = b; dst = ob; off = (i - na8) << 3; }
    float4 x = *(const float4*)(src + off);
    float4 y = *(const float4*)(src + off + 4);
    v8s r;
    r[0] = f2bf(x.x); r[1] = f2bf(x.y); r[2] = f2bf(x.z); r[3] = f2bf(x.w);
    r[4] = f2bf(y.x); r[5] = f2bf(y.y); r[6] = f2bf(y.z); r[7] = f2bf(y.w);
    *(v8s*)(dst + off) = r;
}

// ---------------------------------------------------------------------------
// Transpose-convert W[Kd][Nd] f32 -> Wt[Nd][Kd] bf16 (32x32 LDS tiles)
__global__ __launch_bounds__(256) void tconvW(const float* __restrict__ W,
                                              short* __restrict__ Wt,
                                              int Kd, int Nd) {
    __shared__ float T[32][33];
    int n0 = blockIdx.x * 32, k0 = blockIdx.y * 32;
    int tx = threadIdx.x & 31, ty = threadIdx.x >> 5;
#pragma unroll
    for (int p = 0; p < 4; ++p) {
        int kk = ty + p * 8;
        T[tx][kk] = W[(size_t)(k0 + kk) * Nd + n0 + tx];
    }
    __syncthreads();
#pragma unroll
    for (int p = 0; p < 4; ++p) {
        int nn = ty + p * 8;
        Wt[(size_t)(n0 + nn) * Kd + k0 + tx] = f2bf(T[nn][tx]);
    }
}

// Same, for Wq/Wk/Wv -> contiguous WtQKV (z selects)
__global__ __launch_bounds__(256) void tconv3(const float* __restrict__ W0,
                                              const float* __restrict__ W1,
                                              const float* __restrict__ W2,
                                              short* __restrict__ Wt) {
    __shared__ float T[32][33];
    const float* W = (blockIdx.z == 0) ? W0 : (blockIdx.z == 1) ? W1 : W2;
    short* Wo = Wt + (size_t)blockIdx.z * 768 * 768;
    int n0 = blockIdx.x * 32, k0 = blockIdx.y * 32;
    int tx = threadIdx.x & 31, ty = threadIdx.x >> 5;
#pragma unroll
    for (int p = 0; p < 4; ++p) {
        int kk = ty + p * 8;
        T[tx][kk] = W[(size_t)(k0 + kk) * 768 + n0 + tx];
    }
    __syncthreads();
#pragma unroll
    for (int p = 0; p < 4; ++p) {
        int nn = ty + p * 8;
        Wo[(size_t)(n0 + nn) * 768 + k0 + tx] = f2bf(T[nn][tx]);
    }
}

// ---------------------------------------------------------------------------
// Build transposed hash-projection weight in bf16: hpwT[hc][kk], kk in [0,896)
//   kk < 768 : hash_proj[h][kk][c] ; kk >= 768: 0.1*hash_proj[h][kk-768][c]
__global__ __launch_bounds__(256) void build_hpwT(const float* __restrict__ hp,
                                                  short* __restrict__ hpwT) {
    __shared__ float T[32][33];
    int kk0 = blockIdx.x * 32, hc0 = blockIdx.y * 32;
    int h = hc0 >> 6, cb = hc0 & 63;
    int tx = threadIdx.x & 31, ty = threadIdx.x >> 5;
#pragma unroll
    for (int p = 0; p < 4; ++p) {
        int kp = ty + p * 8;
        int gk = kk0 + kp;
        int ks = (gk >= 768) ? gk - 768 : gk;
        float f = hp[((size_t)h * 768 + ks) * 64 + cb + tx];
        T[tx][kp] = (gk >= 768) ? 0.1f * f : f;
    }
    __syncthreads();
#pragma unroll
    for (int p = 0; p < 4; ++p) {
        int cp = ty + p * 8;
        hpwT[(size_t)(hc0 + cp) * 896 + kk0 + tx] = f2bf(T[cp][tx]);
    }
}

// ---------------------------------------------------------------------------
// MFMA bf16 GEMM: out = concat(A[K1],A2[K2]) @ Bt^T (+bias), f32 accumulate.
// Bt is PRE-TRANSPOSED: Bt[n][k] row-major bf16.
// Tiles BM=128 BN=64 BK=64, 4 waves (2x2), 16x16x32 MFMA.
// mode 0: f32 store (+bias if non-null) to outF[gr*N+gc]
// mode 1: QKV scatter to outF + which*3145728, layout [B,H,S,HD]
// mode 2: gate: g=sigmoid(acc+bias); outB = bf16(g*gctx + (1-g)*ghs)
__global__ __launch_bounds__(256) void gemm_mfma(
    const short* __restrict__ A, const short* __restrict__ A2,
    const short* __restrict__ Bt, const float* __restrict__ bias,
    float* __restrict__ outF, short* __restrict__ outB,
    int N, int K1, int K2, int mode, int nsub,
    const float* __restrict__ gctx, const float* __restrict__ ghs) {
    __shared__ short As[128][72];   // 144B rows: 16B-aligned, conflict-free b128
    __shared__ short Bs[64][72];
    const int t = threadIdx.x;
    const int lane = t & 63, wave = t >> 6;
    const int wm = wave >> 1, wn = wave & 1;
    const int l15 = lane & 15, l4 = lane >> 4;
    const int which = blockIdx.x / nsub;
    const int col0 = (blockIdx.x % nsub) * 64;
    const int row0 = blockIdx.y * 128;
    const short* Bp = Bt + (size_t)which * 589824;
    const int K = K1 + K2;
    v4f acc[4][2];
#pragma unroll
    for (int m = 0; m < 4; ++m)
#pragma unroll
        for (int n = 0; n < 2; ++n) acc[m][n] = (v4f){0.f, 0.f, 0.f, 0.f};

    for (int k0 = 0; k0 < K; k0 += 64) {
        const short* Ap; int ks, Astride;
        if (k0 < K1) { Ap = A;  ks = k0;      Astride = K1; }
        else         { Ap = A2; ks = k0 - K1; Astride = K2; }
#pragma unroll
        for (int p = 0; p < 4; ++p) {
            int idx = t + (p << 8), r = idx >> 3, c = idx & 7;
            *(int4*)&As[r][c << 3] =
                *(const int4*)(Ap + (size_t)(row0 + r) * Astride + ks + (c << 3));
        }
#pragma unroll
        for (int p = 0; p < 2; ++p) {
            int idx = t + (p << 8), r = idx >> 3, c = idx & 7;
            *(int4*)&Bs[r][c << 3] =
                *(const int4*)(Bp + (size_t)(col0 + r) * K + k0 + (c << 3));
        }
        __syncthreads();
#pragma unroll
        for (int kk = 0; kk < 2; ++kk) {
            v8s a0 = *(const v8s*)&As[(wm * 4 + 0) * 16 + l15][kk * 32 + l4 * 8];
            v8s a1 = *(const v8s*)&As[(wm * 4 + 1) * 16 + l15][kk * 32 + l4 * 8];
            v8s a2 = *(const v8s*)&As[(wm * 4 + 2) * 16 + l15][kk * 32 + l4 * 8];
            v8s a3 = *(const v8s*)&As[(wm * 4 + 3) * 16 + l15][kk * 32 + l4 * 8];
            v8s b0 = *(const v8s*)&Bs[(wn * 2 + 0) * 16 + l15][kk * 32 + l4 * 8];
            v8s b1 = *(const v8s*)&Bs[(wn * 2 + 1) * 16 + l15][kk * 32 + l4 * 8];
            acc[0][0] = __builtin_amdgcn_mfma_f32_16x16x32_bf16(a0, b0, acc[0][0], 0, 0, 0);
            acc[0][1] = __builtin_amdgcn_mfma_f32_16x16x32_bf16(a0, b1, acc[0][1], 0, 0, 0);
            acc[1][0] = __builtin_amdgcn_mfma_f32_16x16x32_bf16(a1, b0, acc[1][0], 0, 0, 0);
            acc[1][1] = __builtin_amdgcn_mfma_f32_16x16x32_bf16(a1, b1, acc[1][1], 0, 0, 0);
            acc[2][0] = __builtin_amdgcn_mfma_f32_16x16x32_bf16(a2, b0, acc[2][0], 0, 0, 0);
            acc[2][1] = __builtin_amdgcn_mfma_f32_16x16x32_bf16(a2, b1, acc[2][1], 0, 0, 0);
            acc[3][0] = __builtin_amdgcn_mfma_f32_16x16x32_bf16(a3, b0, acc[3][0], 0, 0, 0);
            acc[3][1] = __builtin_amdgcn_mfma_f32_16x16x32_bf16(a3, b1, acc[3][1], 0, 0, 0);
        }
        __syncthreads();
    }
    // epilogue: D row=(l>>4)*4+i, col=l&15 within each 16x16 fragment
#pragma unroll
    for (int m = 0; m < 4; ++m) {
#pragma unroll
        for (int n = 0; n < 2; ++n) {
            int gr0 = row0 + (wm * 4 + m) * 16 + l4 * 4;
            int gc = col0 + (wn * 2 + n) * 16 + l15;
#pragma unroll
            for (int i = 0; i < 4; ++i) {
                int gr = gr0 + i;
                float c = acc[m][n][i];
                if (mode == 0) {
                    if (bias) c += bias[gc];
                    outF[(size_t)gr * N + gc] = c;
                } else if (mode == 1) {
                    int bb = gr >> 11, s = gr & 2047;
                    int h = gc >> 6, hd = gc & 63;
                    outF[(size_t)which * 3145728 +
                         (((size_t)(bb * HH + h)) * SS + s) * HDIM + hd] = c;
                } else {
                    c += bias[gc];
                    float g = 1.f / (1.f + __expf(-c));
                    size_t off = (size_t)gr * N + gc;
                    outB[off] = f2bf(g * gctx[off] + (1.f - g) * ghs[off]);
                }
            }
        }
    }
}

// ---------------------------------------------------------------------------
// Pack sign bits of proj[4096][512] into codes[4096][8] u64 via wave ballot
__global__ __launch_bounds__(512) void pack_codes(const float* __restrict__ proj,
                                                  unsigned long long* __restrict__ codes) {
    int row = blockIdx.x, t = threadIdx.x;
    float v = proj[(size_t)row * 512 + t];
    unsigned long long bal = __ballot(v > 0.f);
    if ((t & 63) == 0) codes[(size_t)row * NWORDS + (t >> 6)] = bal;
}

// ---------------------------------------------------------------------------
// Precompute LSH keep masks ONCE per batch.
__global__ __launch_bounds__(512) void mask_kernel(
    const unsigned long long* __restrict__ codes, const int* __restrict__ mask,
    unsigned long long* __restrict__ keepArr, unsigned int* __restrict__ chunkmask) {
    __shared__ unsigned long long ckS[64][NWORDS];
    __shared__ int mskS[64];
    __shared__ unsigned int cmaskS;
    const int t = threadIdx.x;
    const int r = t >> 3, tx = t & 7;
    const int q0 = blockIdx.x << 6, b = blockIdx.y;

    unsigned long long cq[NWORDS];
    {
        const unsigned long long* cp = codes + ((size_t)(b * SS + q0 + r)) * NWORDS;
#pragma unroll
        for (int w = 0; w < NWORDS; ++w) cq[w] = cp[w];
    }
    if (t == 0) cmaskS = 0u;

    for (int kc = 0; kc < 32; ++kc) {
        __syncthreads();
        {
            int jr = t >> 3, ww = t & 7;
            ckS[jr][ww ^ (jr >> 3)] =
                codes[((size_t)(b * SS + (kc << 6) + jr)) * NWORDS + ww];
        }
        if (t < 64) mskS[t] = mask[b * SS + (kc << 6) + t];
        __syncthreads();

        unsigned int keep8 = 0;
#pragma unroll
        for (int j8 = 0; j8 < 8; ++j8) {
            int j = (tx << 3) + j8;
            int ham = 0;
#pragma unroll
            for (int w = 0; w < NWORDS; ++w)
                ham += __popcll(cq[w] ^ ckS[j][w ^ tx]);
            if (ham <= HAM_MAX && mskS[j]) keep8 |= (1u << j8);
        }
        unsigned long long k64 = 0;
#pragma unroll
        for (int i = 0; i < 8; ++i)
            k64 |= ((unsigned long long)(__shfl(keep8, i, 8) & 0xFFu)) << (8 * i);
        if (tx == 0) keepArr[((size_t)(b * SS + q0 + r)) * 32 + kc] = k64;
        if (keep8) atomicOr(&cmaskS, 1u << kc);
    }
    __syncthreads();
    if (t == 0) chunkmask[b * 32 + blockIdx.x] = cmaskS;
}

// ---------------------------------------------------------------------------
// Fused LSH attention: iterate ONLY active chunks; writes ctx f32 + bf16.
__global__ __launch_bounds__(256) void attn_kernel(
    const float* __restrict__ qm, const float* __restrict__ km,
    const float* __restrict__ vm, const unsigned long long* __restrict__ keepArr,
    const unsigned int* __restrict__ chunkmask, float* __restrict__ ctx,
    short* __restrict__ ctxbf) {
    __shared__ float Qs[64][68], Ks[64][68], Vs[64][68];
    const int t = threadIdx.x;
    const int r = t >> 2, tx = t & 3;
    const int q0 = blockIdx.x << 6;
    const int bh = blockIdx.y;
    const int b = bh / HH, h = bh % HH;

    const float* qbase = qm + ((size_t)bh * SS + q0) * HDIM;
#pragma unroll
    for (int i = 0; i < 4; ++i) {
        int idx = t + (i << 8);
        int rr = idx >> 4, c4 = (idx & 15) << 2;
        *(float4*)&Qs[rr][c4] = *(const float4*)(qbase + rr * HDIM + c4);
    }
    unsigned int cm = chunkmask[b * 32 + blockIdx.x];
    const size_t rowIdx = (size_t)(b * SS + q0 + r);

    float mrun = -1e30f, lrun = 0.f;
    float acc[16];
#pragma unroll
    for (int i = 0; i < 16; ++i) acc[i] = 0.f;

    const float* kbase0 = km + (size_t)bh * SS * HDIM;
    const float* vbase0 = vm + (size_t)bh * SS * HDIM;

    while (cm) {
        int kc = __ffs(cm) - 1;
        cm &= cm - 1;
        unsigned long long k64 = keepArr[rowIdx * 32 + kc];
        unsigned int keep16 = (unsigned int)(k64 >> (tx << 4)) & 0xFFFFu;

        __syncthreads();
        const float* kb = kbase0 + ((size_t)kc << 6) * HDIM;
        const float* vb = vbase0 + ((size_t)kc << 6) * HDIM;
#pragma unroll
        for (int i = 0; i < 4; ++i) {
            int idx = t + (i << 8);
            int rr = idx >> 4, c4 = (idx & 15) << 2;
            *(float4*)&Ks[rr][c4 ^ ((rr >> 4) << 2)] = *(const float4*)(kb + rr * HDIM + c4);
            *(float4*)&Vs[rr][c4] = *(const float4*)(vb + rr * HDIM + c4);
        }
        __syncthreads();

        float p[16];
#pragma unroll
        for (int j16 = 0; j16 < 16; ++j16) p[j16] = 0.f;
        for (int d4 = 0; d4 < 64; d4 += 4) {
            float4 q4 = *(const float4*)&Qs[r][d4];
#pragma unroll
            for (int j16 = 0; j16 < 16; ++j16) {
                float4 k4 = *(const float4*)&Ks[(tx << 4) + j16][d4 ^ (tx << 2)];
                p[j16] += q4.x * k4.x + q4.y * k4.y + q4.z * k4.z + q4.w * k4.w;
            }
        }
        float mloc = -1e30f;
#pragma unroll
        for (int j16 = 0; j16 < 16; ++j16) {
            float sv = (keep16 >> j16 & 1) ? p[j16] * 0.125f : -1e30f;
            p[j16] = sv;
            mloc = fmaxf(mloc, sv);
        }
        mloc = fmaxf(mloc, __shfl_xor(mloc, 1, 4));
        mloc = fmaxf(mloc, __shfl_xor(mloc, 2, 4));
        float mnew = fmaxf(mrun, mloc);
        float psum = 0.f;
#pragma unroll
        for (int j16 = 0; j16 < 16; ++j16) {
            float pe = (keep16 >> j16 & 1) ? __expf(p[j16] - mnew) : 0.f;
            p[j16] = pe;
            psum += pe;
        }
        psum += __shfl_xor(psum, 1, 4);
        psum += __shfl_xor(psum, 2, 4);
        float scale = __expf(mrun - mnew);
        lrun = lrun * scale + psum;
#pragma unroll
        for (int i = 0; i < 16; ++i) acc[i] *= scale;
        mrun = mnew;
#pragma unroll
        for (int j = 0; j < 64; ++j) {
            float pj = __shfl(p[j & 15], j >> 4, 4);
#pragma unroll
            for (int i4 = 0; i4 < 4; ++i4) {
                float4 v4 = *(const float4*)&Vs[j][(tx << 4) + (i4 << 2)];
                acc[i4 * 4 + 0] = fmaf(pj, v4.x, acc[i4 * 4 + 0]);
                acc[i4 * 4 + 1] = fmaf(pj, v4.y, acc[i4 * 4 + 1]);
                acc[i4 * 4 + 2] = fmaf(pj, v4.z, acc[i4 * 4 + 2]);
                acc[i4 * 4 + 3] = fmaf(pj, v4.w, acc[i4 * 4 + 3]);
            }
        }
    }
    float invl = lrun > 0.f ? 1.f / lrun : 0.f;
    size_t base = ((size_t)b * SS + q0 + r) * DD + h * HDIM + (tx << 4);
    float* cb = ctx + base;
    short* cbb = ctxbf + base;
#pragma unroll
    for (int i = 0; i < 16; ++i) {
        float val = acc[i] * invl;
        cb[i] = val;
        cbb[i] = f2bf(val);
    }
}

// ---------------------------------------------------------------------------
extern "C" void kernel_launch(void* const* d_in, const int* in_sizes, int n_in,
                              void* d_out, int out_size, void* d_ws, size_t ws_size,
                              hipStream_t stream) {
    const float* hs = (const float*)d_in[0];
    const float* tf = (const float*)d_in[1];
    const float* Wq = (const float*)d_in[2];
    const float* Wk = (const float*)d_in[3];
    const float* Wv = (const float*)d_in[4];
    const float* Wo = (const float*)d_in[5];
    const float* bo = (const float*)d_in[6];
    const float* Wg = (const float*)d_in[7];
    const float* bg = (const float*)d_in[8];
    const float* hp = (const float*)d_in[9];
    const float* tb = (const float*)d_in[10];
    const int* msk  = (const int*)d_in[11];
    float* out = (float*)d_out;

    char* w = (char*)d_ws;
    float* q      = (float*)(w + OFF_Q);
    float* ctx    = (float*)(w + OFF_CTX);
    float* proj   = (float*)(w + OFF_PROJ);
    short* hsbf   = (short*)(w + OFF_HSBF);
    short* tfbf   = (short*)(w + OFF_TFBF);
    short* ctxbf  = (short*)(w + OFF_CTXBF);
    short* wtqkv  = (short*)(w + OFF_WTQKV);
    short* ctx2bf = (short*)(w + OFF_CTX2BF);
    short* hpwT   = (short*)(w + OFF_HPWT);
    short* wgT    = (short*)(w + OFF_WGT);
    short* woT    = (short*)(w + OFF_WOT);
    unsigned long long* codes = (unsigned long long*)(w + OFF_CODES);
    unsigned long long* keepA = (unsigned long long*)(w + OFF_KEEP);
    unsigned int* cmask = (unsigned int*)(w + OFF_CMASK);

    // 1. activations -> bf16
    conv_act<<<dim3((3145728 / 8 + 524288 / 8 + 255) / 256), 256, 0, stream>>>(
        hs, 3145728 / 8, tf, 524288 / 8, hsbf, tfbf);
    // 2-4. weights -> transposed bf16
    tconv3<<<dim3(24, 24, 3), 256, 0, stream>>>(Wq, Wk, Wv, wtqkv);
    tconvW<<<dim3(24, 28), 256, 0, stream>>>(Wg, wgT, 896, 768);
    build_hpwT<<<dim3(28, 16), 256, 0, stream>>>(hp, hpwT);
    // 5. fused QKV (scatter to [B,H,S,HD], q/k/v contiguous)
    gemm_mfma<<<dim3(36, 32), 256, 0, stream>>>(
        hsbf, nullptr, wtqkv, nullptr, q, nullptr, 768, 768, 0, 1, 12, nullptr, nullptr);
    // 6. LSH projection -> proj f32
    gemm_mfma<<<dim3(8, 32), 256, 0, stream>>>(
        hsbf, tfbf, hpwT, tb, proj, nullptr, 512, 768, 128, 0, 8, nullptr, nullptr);
    // 7-9. codes, masks, attention
    pack_codes<<<4096, 512, 0, stream>>>(proj, codes);
    mask_kernel<<<dim3(32, 2), 512, 0, stream>>>(codes, msk, keepA, cmask);
    attn_kernel<<<dim3(32, 24), 256, 0, stream>>>(
        q, q + 3145728, q + 2 * 3145728, keepA, cmask, ctx, ctxbf);
    // 10. gate GEMM + sigmoid-blend epilogue -> ctx2 bf16
    gemm_mfma<<<dim3(12, 32), 256, 0, stream>>>(
        ctxbf, tfbf, wgT, bg, nullptr, ctx2bf, 768, 768, 128, 2, 12, ctx, hs);
    // 11. transpose Wo late (into dead ctx region)
    tconvW<<<dim3(24, 24), 256, 0, stream>>>(Wo, woT, 768, 768);
    // 12. output projection -> d_out f32
    gemm_mfma<<<dim3(12, 32), 256, 0, stream>>>(
        ctx2bf, nullptr, woT, bo, out, nullptr, 768, 768, 0, 0, 12, nullptr, nullptr);
}

// Round 4
// 164.967 us; speedup vs baseline: 4.6163x; 1.3214x over previous
//
#include <hip/hip_runtime.h>

typedef __attribute__((ext_vector_type(4))) float v4f;
typedef __attribute__((ext_vector_type(8))) short v8s;

// Problem constants
#define BB 2
#define SS 2048
#define DD 768
#define HH 12
#define HDIM 64
#define NWORDS 8          // 512 hash bits = 8 u64
#define HAM_MAX 179       // sim > 0.3  <=>  hamming <= 179

// ws layout (bytes), max use 72.94 MB (ws proven >= 73.4 MB)
#define OFF_Q      ((size_t)0)
#define OFF_K      ((size_t)12582912)
#define OFF_V      ((size_t)25165824)
#define OFF_CTX    ((size_t)37748736)   // ctx f32 (after attn); proj f32 before; WoT after gate
#define OFF_PROJ   OFF_CTX
#define OFF_WOT    OFF_CTX
#define OFF_HSBF   ((size_t)50331648)
#define OFF_TFBF   ((size_t)56623104)
#define OFF_CTXBF  ((size_t)57671680)   // ctx bf16 (attn out); WtQKV before attn
#define OFF_WTQKV  OFF_CTXBF
#define OFF_CTX2BF ((size_t)63963136)
#define OFF_CODES  ((size_t)70254592)
#define OFF_KEEP   ((size_t)70516736)   // keepArr; hpwT before mask_kernel
#define OFF_HPWT   OFF_KEEP
#define OFF_CMASK  ((size_t)71565312)
#define OFF_WGT    ((size_t)71565568)

__device__ inline short f2bf(float x) {
    unsigned u = __float_as_uint(x);
    u = (u + 0x7FFFu + ((u >> 16) & 1u)) >> 16;  // RNE
    return (short)u;
}

// ---------------------------------------------------------------------------
// Convert activations f32 -> bf16 (hs and tf in one launch)
__global__ __launch_bounds__(256) void conv_act(
    const float* __restrict__ a, int na8, const float* __restrict__ b, int nb8,
    short* __restrict__ oa, short* __restrict__ ob) {
    int i = blockIdx.x * 256 + threadIdx.x;
    if (i >= na8 + nb8) return;
    const float* src; short* dst; int off;
    if (i < na8) { src = a; dst = oa; off = i << 3; }
    else         { src = b; dst = ob; off = (i - na8) << 3; }
    float4 x = *(const float4*)(src + off);
    float4 y = *(const float4*)(src + off + 4);
    v8s r;
    r[0] = f2bf(x.x); r[1] = f2bf(x.y); r[2] = f2bf(x.z); r[3] = f2bf(x.w);
    r[4] = f2bf(y.x); r[5] = f2bf(y.y); r[6] = f2bf(y.z); r[7] = f2bf(y.w);
    *(v8s*)(dst + off) = r;
}

// ---------------------------------------------------------------------------
// Transpose-convert W[Kd][Nd] f32 -> Wt[Nd][Kd] bf16 (32x32 LDS tiles)
__global__ __launch_bounds__(256) void tconvW(const float* __restrict__ W,
                                              short* __restrict__ Wt,
                                              int Kd, int Nd) {
    __shared__ float T[32][33];
    int n0 = blockIdx.x * 32, k0 = blockIdx.y * 32;
    int tx = threadIdx.x & 31, ty = threadIdx.x >> 5;
#pragma unroll
    for (int p = 0; p < 4; ++p) {
        int kk = ty + p * 8;
        T[tx][kk] = W[(size_t)(k0 + kk) * Nd + n0 + tx];
    }
    __syncthreads();
#pragma unroll
    for (int p = 0; p < 4; ++p) {
        int nn = ty + p * 8;
        Wt[(size_t)(n0 + nn) * Kd + k0 + tx] = f2bf(T[nn][tx]);
    }
}

// Same, for Wq/Wk/Wv -> contiguous WtQKV (z selects)
__global__ __launch_bounds__(256) void tconv3(const float* __restrict__ W0,
                                              const float* __restrict__ W1,
                                              const float* __restrict__ W2,
                                              short* __restrict__ Wt) {
    __shared__ float T[32][33];
    const float* W = (blockIdx.z == 0) ? W0 : (blockIdx.z == 1) ? W1 : W2;
    short* Wo = Wt + (size_t)blockIdx.z * 768 * 768;
    int n0 = blockIdx.x * 32, k0 = blockIdx.y * 32;
    int tx = threadIdx.x & 31, ty = threadIdx.x >> 5;
#pragma unroll
    for (int p = 0; p < 4; ++p) {
        int kk = ty + p * 8;
        T[tx][kk] = W[(size_t)(k0 + kk) * 768 + n0 + tx];
    }
    __syncthreads();
#pragma unroll
    for (int p = 0; p < 4; ++p) {
        int nn = ty + p * 8;
        Wo[(size_t)(n0 + nn) * 768 + k0 + tx] = f2bf(T[nn][tx]);
    }
}

// ---------------------------------------------------------------------------
// Build transposed hash-projection weight in bf16: hpwT[hc][kk], kk in [0,896)
__global__ __launch_bounds__(256) void build_hpwT(const float* __restrict__ hp,
                                                  short* __restrict__ hpwT) {
    __shared__ float T[32][33];
    int kk0 = blockIdx.x * 32, hc0 = blockIdx.y * 32;
    int h = hc0 >> 6, cb = hc0 & 63;
    int tx = threadIdx.x & 31, ty = threadIdx.x >> 5;
#pragma unroll
    for (int p = 0; p < 4; ++p) {
        int kp = ty + p * 8;
        int gk = kk0 + kp;
        int ks = (gk >= 768) ? gk - 768 : gk;
        float f = hp[((size_t)h * 768 + ks) * 64 + cb + tx];
        T[tx][kp] = (gk >= 768) ? 0.1f * f : f;
    }
    __syncthreads();
#pragma unroll
    for (int p = 0; p < 4; ++p) {
        int cp = ty + p * 8;
        hpwT[(size_t)(hc0 + cp) * 896 + kk0 + tx] = f2bf(T[cp][tx]);
    }
}

// ---------------------------------------------------------------------------
// MFMA bf16 GEMM: out = concat(A[K1],A2[K2]) @ Bt^T (+bias), f32 accumulate.
// Bt is PRE-TRANSPOSED: Bt[n][k] row-major bf16.
// Tiles BM=128 BN=64 BK=64, 4 waves (2x2), 16x16x32 MFMA.
__global__ __launch_bounds__(256) void gemm_mfma(
    const short* __restrict__ A, const short* __restrict__ A2,
    const short* __restrict__ Bt, const float* __restrict__ bias,
    float* __restrict__ outF, short* __restrict__ outB,
    int N, int K1, int K2, int mode, int nsub,
    const float* __restrict__ gctx, const float* __restrict__ ghs) {
    __shared__ short As[128][72];   // 144B rows: 16B-aligned, conflict-free b128
    __shared__ short Bs[64][72];
    const int t = threadIdx.x;
    const int lane = t & 63, wave = t >> 6;
    const int wm = wave >> 1, wn = wave & 1;
    const int l15 = lane & 15, l4 = lane >> 4;
    const int which = blockIdx.x / nsub;
    const int col0 = (blockIdx.x % nsub) * 64;
    const int row0 = blockIdx.y * 128;
    const short* Bp = Bt + (size_t)which * 589824;
    const int K = K1 + K2;
    v4f acc[4][2];
#pragma unroll
    for (int m = 0; m < 4; ++m)
#pragma unroll
        for (int n = 0; n < 2; ++n) acc[m][n] = (v4f){0.f, 0.f, 0.f, 0.f};

    for (int k0 = 0; k0 < K; k0 += 64) {
        const short* Ap; int ks, Astride;
        if (k0 < K1) { Ap = A;  ks = k0;      Astride = K1; }
        else         { Ap = A2; ks = k0 - K1; Astride = K2; }
#pragma unroll
        for (int p = 0; p < 4; ++p) {
            int idx = t + (p << 8), r = idx >> 3, c = idx & 7;
            *(int4*)&As[r][c << 3] =
                *(const int4*)(Ap + (size_t)(row0 + r) * Astride + ks + (c << 3));
        }
#pragma unroll
        for (int p = 0; p < 2; ++p) {
            int idx = t + (p << 8), r = idx >> 3, c = idx & 7;
            *(int4*)&Bs[r][c << 3] =
                *(const int4*)(Bp + (size_t)(col0 + r) * K + k0 + (c << 3));
        }
        __syncthreads();
#pragma unroll
        for (int kk = 0; kk < 2; ++kk) {
            v8s a0 = *(const v8s*)&As[(wm * 4 + 0) * 16 + l15][kk * 32 + l4 * 8];
            v8s a1 = *(const v8s*)&As[(wm * 4 + 1) * 16 + l15][kk * 32 + l4 * 8];
            v8s a2 = *(const v8s*)&As[(wm * 4 + 2) * 16 + l15][kk * 32 + l4 * 8];
            v8s a3 = *(const v8s*)&As[(wm * 4 + 3) * 16 + l15][kk * 32 + l4 * 8];
            v8s b0 = *(const v8s*)&Bs[(wn * 2 + 0) * 16 + l15][kk * 32 + l4 * 8];
            v8s b1 = *(const v8s*)&Bs[(wn * 2 + 1) * 16 + l15][kk * 32 + l4 * 8];
            acc[0][0] = __builtin_amdgcn_mfma_f32_16x16x32_bf16(a0, b0, acc[0][0], 0, 0, 0);
            acc[0][1] = __builtin_amdgcn_mfma_f32_16x16x32_bf16(a0, b1, acc[0][1], 0, 0, 0);
            acc[1][0] = __builtin_amdgcn_mfma_f32_16x16x32_bf16(a1, b0, acc[1][0], 0, 0, 0);
            acc[1][1] = __builtin_amdgcn_mfma_f32_16x16x32_bf16(a1, b1, acc[1][1], 0, 0, 0);
            acc[2][0] = __builtin_amdgcn_mfma_f32_16x16x32_bf16(a2, b0, acc[2][0], 0, 0, 0);
            acc[2][1] = __builtin_amdgcn_mfma_f32_16x16x32_bf16(a2, b1, acc[2][1], 0, 0, 0);
            acc[3][0] = __builtin_amdgcn_mfma_f32_16x16x32_bf16(a3, b0, acc[3][0], 0, 0, 0);
            acc[3][1] = __builtin_amdgcn_mfma_f32_16x16x32_bf16(a3, b1, acc[3][1], 0, 0, 0);
        }
        __syncthreads();
    }
#pragma unroll
    for (int m = 0; m < 4; ++m) {
#pragma unroll
        for (int n = 0; n < 2; ++n) {
            int gr0 = row0 + (wm * 4 + m) * 16 + l4 * 4;
            int gc = col0 + (wn * 2 + n) * 16 + l15;
#pragma unroll
            for (int i = 0; i < 4; ++i) {
                int gr = gr0 + i;
                float c = acc[m][n][i];
                if (mode == 0) {
                    if (bias) c += bias[gc];
                    outF[(size_t)gr * N + gc] = c;
                } else if (mode == 1) {
                    int bb = gr >> 11, s = gr & 2047;
                    int h = gc >> 6, hd = gc & 63;
                    outF[(size_t)which * 3145728 +
                         (((size_t)(bb * HH + h)) * SS + s) * HDIM + hd] = c;
                } else {
                    c += bias[gc];
                    float g = 1.f / (1.f + __expf(-c));
                    size_t off = (size_t)gr * N + gc;
                    outB[off] = f2bf(g * gctx[off] + (1.f - g) * ghs[off]);
                }
            }
        }
    }
}

// ---------------------------------------------------------------------------
// Pack sign bits of proj[4096][512] into codes[4096][8] u64 via wave ballot.
// Block 0 also zero-inits the chunkmask bitmap (consumed later by mask_kernel).
__global__ __launch_bounds__(512) void pack_codes(const float* __restrict__ proj,
                                                  unsigned long long* __restrict__ codes,
                                                  unsigned int* __restrict__ cmask) {
    int row = blockIdx.x, t = threadIdx.x;
    if (row == 0 && t < 64) cmask[t] = 0u;
    float v = proj[(size_t)row * 512 + t];
    unsigned long long bal = __ballot(v > 0.f);
    if ((t & 63) == 0) codes[(size_t)row * NWORDS + (t >> 6)] = bal;
}

// ---------------------------------------------------------------------------
// LSH keep masks v2: one (qchunk, kchunk, b) tile per block, 2048 blocks.
// 256 threads: r = t>>2 (q row), tx = t&3 (16 keys each).
__global__ __launch_bounds__(256) void mask_kernel(
    const unsigned long long* __restrict__ codes, const int* __restrict__ mask,
    unsigned long long* __restrict__ keepArr, unsigned int* __restrict__ chunkmask) {
    __shared__ unsigned long long ckS[64][NWORDS];
    __shared__ int mskS[64];
    const int t = threadIdx.x;
    const int r = t >> 2, tx = t & 3;
    const int qc = blockIdx.x, kc = blockIdx.y, b = blockIdx.z;
    const int q0 = qc << 6, k0 = kc << 6;

    // stage 64 key codes, word-slot XOR-swizzled by row>>4 (matches read: tx)
#pragma unroll
    for (int p = 0; p < 2; ++p) {
        int idx = t + (p << 8);
        int jr = idx >> 3, ww = idx & 7;
        ckS[jr][ww ^ (jr >> 4)] =
            codes[((size_t)(b * SS + k0 + jr)) * NWORDS + ww];
    }
    if (t < 64) mskS[t] = mask[b * SS + k0 + t];
    // own q-row codes -> regs (4 threads share a row; L1/L2 serves the repeat)
    unsigned long long cq[NWORDS];
    {
        const unsigned long long* cp = codes + ((size_t)(b * SS + q0 + r)) * NWORDS;
#pragma unroll
        for (int w = 0; w < NWORDS; ++w) cq[w] = cp[w];
    }
    __syncthreads();

    unsigned long long k64 = 0;
#pragma unroll
    for (int j16 = 0; j16 < 16; ++j16) {
        int j = (tx << 4) + j16;
        int ham = 0;
#pragma unroll
        for (int w = 0; w < NWORDS; ++w)
            ham += __popcll(cq[w] ^ ckS[j][w ^ tx]);
        if (ham <= HAM_MAX && mskS[j]) k64 |= 1ull << j;
    }
    // OR across the 4 lanes of this q-row
    k64 |= __shfl_xor(k64, 1, 4);
    k64 |= __shfl_xor(k64, 2, 4);
    if (tx == 0) keepArr[((size_t)(b * SS + q0 + r)) * 32 + kc] = k64;
    if (__syncthreads_or(k64 != 0) && t == 0)
        atomicOr(&chunkmask[b * 32 + qc], 1u << kc);
}

// ---------------------------------------------------------------------------
// Fused LSH attention: iterate ONLY active chunks; writes ctx f32 + bf16.
__global__ __launch_bounds__(256) void attn_kernel(
    const float* __restrict__ qm, const float* __restrict__ km,
    const float* __restrict__ vm, const unsigned long long* __restrict__ keepArr,
    const unsigned int* __restrict__ chunkmask, float* __restrict__ ctx,
    short* __restrict__ ctxbf) {
    __shared__ float Qs[64][68], Ks[64][68], Vs[64][68];
    const int t = threadIdx.x;
    const int r = t >> 2, tx = t & 3;
    const int q0 = blockIdx.x << 6;
    const int bh = blockIdx.y;
    const int b = bh / HH, h = bh % HH;

    const float* qbase = qm + ((size_t)bh * SS + q0) * HDIM;
#pragma unroll
    for (int i = 0; i < 4; ++i) {
        int idx = t + (i << 8);
        int rr = idx >> 4, c4 = (idx & 15) << 2;
        *(float4*)&Qs[rr][c4] = *(const float4*)(qbase + rr * HDIM + c4);
    }
    unsigned int cm = chunkmask[b * 32 + blockIdx.x];
    const size_t rowIdx = (size_t)(b * SS + q0 + r);

    float mrun = -1e30f, lrun = 0.f;
    float acc[16];
#pragma unroll
    for (int i = 0; i < 16; ++i) acc[i] = 0.f;

    const float* kbase0 = km + (size_t)bh * SS * HDIM;
    const float* vbase0 = vm + (size_t)bh * SS * HDIM;

    while (cm) {
        int kc = __ffs(cm) - 1;
        cm &= cm - 1;
        unsigned long long k64 = keepArr[rowIdx * 32 + kc];
        unsigned int keep16 = (unsigned int)(k64 >> (tx << 4)) & 0xFFFFu;

        __syncthreads();
        const float* kb = kbase0 + ((size_t)kc << 6) * HDIM;
        const float* vb = vbase0 + ((size_t)kc << 6) * HDIM;
#pragma unroll
        for (int i = 0; i < 4; ++i) {
            int idx = t + (i << 8);
            int rr = idx >> 4, c4 = (idx & 15) << 2;
            *(float4*)&Ks[rr][c4 ^ ((rr >> 4) << 2)] = *(const float4*)(kb + rr * HDIM + c4);
            *(float4*)&Vs[rr][c4] = *(const float4*)(vb + rr * HDIM + c4);
        }
        __syncthreads();

        float p[16];
#pragma unroll
        for (int j16 = 0; j16 < 16; ++j16) p[j16] = 0.f;
        for (int d4 = 0; d4 < 64; d4 += 4) {
            float4 q4 = *(const float4*)&Qs[r][d4];
#pragma unroll
            for (int j16 = 0; j16 < 16; ++j16) {
                float4 k4 = *(const float4*)&Ks[(tx << 4) + j16][d4 ^ (tx << 2)];
                p[j16] += q4.x * k4.x + q4.y * k4.y + q4.z * k4.z + q4.w * k4.w;
            }
        }
        float mloc = -1e30f;
#pragma unroll
        for (int j16 = 0; j16 < 16; ++j16) {
            float sv = (keep16 >> j16 & 1) ? p[j16] * 0.125f : -1e30f;
            p[j16] = sv;
            mloc = fmaxf(mloc, sv);
        }
        mloc = fmaxf(mloc, __shfl_xor(mloc, 1, 4));
        mloc = fmaxf(mloc, __shfl_xor(mloc, 2, 4));
        float mnew = fmaxf(mrun, mloc);
        float psum = 0.f;
#pragma unroll
        for (int j16 = 0; j16 < 16; ++j16) {
            float pe = (keep16 >> j16 & 1) ? __expf(p[j16] - mnew) : 0.f;
            p[j16] = pe;
            psum += pe;
        }
        psum += __shfl_xor(psum, 1, 4);
        psum += __shfl_xor(psum, 2, 4);
        float scale = __expf(mrun - mnew);
        lrun = lrun * scale + psum;
#pragma unroll
        for (int i = 0; i < 16; ++i) acc[i] *= scale;
        mrun = mnew;
#pragma unroll
        for (int j = 0; j < 64; ++j) {
            float pj = __shfl(p[j & 15], j >> 4, 4);
#pragma unroll
            for (int i4 = 0; i4 < 4; ++i4) {
                float4 v4 = *(const float4*)&Vs[j][(tx << 4) + (i4 << 2)];
                acc[i4 * 4 + 0] = fmaf(pj, v4.x, acc[i4 * 4 + 0]);
                acc[i4 * 4 + 1] = fmaf(pj, v4.y, acc[i4 * 4 + 1]);
                acc[i4 * 4 + 2] = fmaf(pj, v4.z, acc[i4 * 4 + 2]);
                acc[i4 * 4 + 3] = fmaf(pj, v4.w, acc[i4 * 4 + 3]);
            }
        }
    }
    float invl = lrun > 0.f ? 1.f / lrun : 0.f;
    size_t base = ((size_t)b * SS + q0 + r) * DD + h * HDIM + (tx << 4);
    float* cb = ctx + base;
    short* cbb = ctxbf + base;
#pragma unroll
    for (int i = 0; i < 16; ++i) {
        float val = acc[i] * invl;
        cb[i] = val;
        cbb[i] = f2bf(val);
    }
}

// ---------------------------------------------------------------------------
extern "C" void kernel_launch(void* const* d_in, const int* in_sizes, int n_in,
                              void* d_out, int out_size, void* d_ws, size_t ws_size,
                              hipStream_t stream) {
    const float* hs = (const float*)d_in[0];
    const float* tf = (const float*)d_in[1];
    const float* Wq = (const float*)d_in[2];
    const float* Wk = (const float*)d_in[3];
    const float* Wv = (const float*)d_in[4];
    const float* Wo = (const float*)d_in[5];
    const float* bo = (const float*)d_in[6];
    const float* Wg = (const float*)d_in[7];
    const float* bg = (const float*)d_in[8];
    const float* hp = (const float*)d_in[9];
    const float* tb = (const float*)d_in[10];
    const int* msk  = (const int*)d_in[11];
    float* out = (float*)d_out;

    char* w = (char*)d_ws;
    float* q      = (float*)(w + OFF_Q);
    float* ctx    = (float*)(w + OFF_CTX);
    float* proj   = (float*)(w + OFF_PROJ);
    short* hsbf   = (short*)(w + OFF_HSBF);
    short* tfbf   = (short*)(w + OFF_TFBF);
    short* ctxbf  = (short*)(w + OFF_CTXBF);
    short* wtqkv  = (short*)(w + OFF_WTQKV);
    short* ctx2bf = (short*)(w + OFF_CTX2BF);
    short* hpwT   = (short*)(w + OFF_HPWT);
    short* wgT    = (short*)(w + OFF_WGT);
    short* woT    = (short*)(w + OFF_WOT);
    unsigned long long* codes = (unsigned long long*)(w + OFF_CODES);
    unsigned long long* keepA = (unsigned long long*)(w + OFF_KEEP);
    unsigned int* cmask = (unsigned int*)(w + OFF_CMASK);

    // 1. activations -> bf16
    conv_act<<<dim3((3145728 / 8 + 524288 / 8 + 255) / 256), 256, 0, stream>>>(
        hs, 3145728 / 8, tf, 524288 / 8, hsbf, tfbf);
    // 2-4. weights -> transposed bf16
    tconv3<<<dim3(24, 24, 3), 256, 0, stream>>>(Wq, Wk, Wv, wtqkv);
    tconvW<<<dim3(24, 28), 256, 0, stream>>>(Wg, wgT, 896, 768);
    build_hpwT<<<dim3(28, 16), 256, 0, stream>>>(hp, hpwT);
    // 5. fused QKV (scatter to [B,H,S,HD], q/k/v contiguous)
    gemm_mfma<<<dim3(36, 32), 256, 0, stream>>>(
        hsbf, nullptr, wtqkv, nullptr, q, nullptr, 768, 768, 0, 1, 12, nullptr, nullptr);
    // 6. LSH projection -> proj f32
    gemm_mfma<<<dim3(8, 32), 256, 0, stream>>>(
        hsbf, tfbf, hpwT, tb, proj, nullptr, 512, 768, 128, 0, 8, nullptr, nullptr);
    // 7-9. codes (+cmask zero), masks, attention
    pack_codes<<<4096, 512, 0, stream>>>(proj, codes, cmask);
    mask_kernel<<<dim3(32, 32, 2), 256, 0, stream>>>(codes, msk, keepA, cmask);
    attn_kernel<<<dim3(32, 24), 256, 0, stream>>>(
        q, q + 3145728, q + 2 * 3145728, keepA, cmask, ctx, ctxbf);
    // 10. gate GEMM + sigmoid-blend epilogue -> ctx2 bf16
    gemm_mfma<<<dim3(12, 32), 256, 0, stream>>>(
        ctxbf, tfbf, wgT, bg, nullptr, ctx2bf, 768, 768, 128, 2, 12, ctx, hs);
    // 11. transpose Wo late (into dead ctx region)
    tconvW<<<dim3(24, 24), 256, 0, stream>>>(Wo, woT, 768, 768);
    // 12. output projection -> d_out f32
    gemm_mfma<<<dim3(12, 32), 256, 0, stream>>>(
        ctx2bf, nullptr, woT, bo, out, nullptr, 768, 768, 0, 0, 12, nullptr, nullptr);
}

// Round 5
// 151.336 us; speedup vs baseline: 5.0321x; 1.0901x over previous
//
#include <hip/hip_runtime.h>

typedef __attribute__((ext_vector_type(4))) float v4f;
typedef __attribute__((ext_vector_type(8))) short v8s;

// Problem constants
#define BB 2
#define SS 2048
#define DD 768
#define HH 12
#define HDIM 64
#define NWORDS 8          // 512 hash bits = 8 u64
#define HAM_MAX 179       // sim > 0.3  <=>  hamming <= 179

// ws layout (bytes), total ~68.1 MB
#define OFF_QBF    ((size_t)0)             // q,k,v bf16 contiguous 3x6291456
#define OFF_CTX    ((size_t)18874368)      // ctx f32 12582912
#define OFF_HSBF   ((size_t)31457280)      // 6291456
#define OFF_TFBF   ((size_t)37748736)      // 1048576
#define OFF_CTXBF  ((size_t)38797312)      // 6291456
#define OFF_CTX2BF ((size_t)45088768)      // 6291456
#define OFF_WTQKV  ((size_t)51380224)      // 3538944
#define OFF_WGT    ((size_t)54919168)      // 1376256
#define OFF_WOT    ((size_t)56295424)      // 1179648
#define OFF_HPWT   ((size_t)57475072)      // 917504
#define OFF_PROJ   ((size_t)58392576)      // 8388608
#define OFF_CODES  ((size_t)66781184)      // 262144
#define OFF_KEEP   ((size_t)67043328)      // 1048576
#define OFF_CMASK  ((size_t)68091904)      // 256

__device__ inline short f2bf(float x) {
    unsigned u = __float_as_uint(x);
    u = (u + 0x7FFFu + ((u >> 16) & 1u)) >> 16;  // RNE
    return (short)u;
}

// async global->LDS, 16B per lane, wave-uniform LDS base + lane*16
__device__ __forceinline__ void load_lds16(const void* g, void* l) {
    __builtin_amdgcn_global_load_lds((const __attribute__((address_space(1))) void*)g,
                                     (__attribute__((address_space(3))) void*)l,
                                     16, 0, 0);
}

// ---------------------------------------------------------------------------
// Convert activations f32 -> bf16 (hs and tf in one launch)
__global__ __launch_bounds__(256) void conv_act(
    const float* __restrict__ a, int na8, const float* __restrict__ b, int nb8,
    short* __restrict__ oa, short* __restrict__ ob) {
    int i = blockIdx.x * 256 + threadIdx.x;
    if (i >= na8 + nb8) return;
    const float* src; short* dst; int off;
    if (i < na8) { src = a; dst = oa; off = i << 3; }
    else         { src = b; dst = ob; off = (i - na8) << 3; }
    float4 x = *(const float4*)(src + off);
    float4 y = *(const float4*)(src + off + 4);
    v8s r;
    r[0] = f2bf(x.x); r[1] = f2bf(x.y); r[2] = f2bf(x.z); r[3] = f2bf(x.w);
    r[4] = f2bf(y.x); r[5] = f2bf(y.y); r[6] = f2bf(y.z); r[7] = f2bf(y.w);
    *(v8s*)(dst + off) = r;
}

// ---------------------------------------------------------------------------
// Transpose-convert W[Kd][Nd] f32 -> Wt[Nd][Kd] bf16 (32x32 LDS tiles)
__global__ __launch_bounds__(256) void tconvW(const float* __restrict__ W,
                                              short* __restrict__ Wt,
                                              int Kd, int Nd) {
    __shared__ float T[32][33];
    int n0 = blockIdx.x * 32, k0 = blockIdx.y * 32;
    int tx = threadIdx.x & 31, ty = threadIdx.x >> 5;
#pragma unroll
    for (int p = 0; p < 4; ++p) {
        int kk = ty + p * 8;
        T[tx][kk] = W[(size_t)(k0 + kk) * Nd + n0 + tx];
    }
    __syncthreads();
#pragma unroll
    for (int p = 0; p < 4; ++p) {
        int nn = ty + p * 8;
        Wt[(size_t)(n0 + nn) * Kd + k0 + tx] = f2bf(T[nn][tx]);
    }
}

// Same, for Wq/Wk/Wv -> contiguous WtQKV (z selects)
__global__ __launch_bounds__(256) void tconv3(const float* __restrict__ W0,
                                              const float* __restrict__ W1,
                                              const float* __restrict__ W2,
                                              short* __restrict__ Wt) {
    __shared__ float T[32][33];
    const float* W = (blockIdx.z == 0) ? W0 : (blockIdx.z == 1) ? W1 : W2;
    short* Wo = Wt + (size_t)blockIdx.z * 768 * 768;
    int n0 = blockIdx.x * 32, k0 = blockIdx.y * 32;
    int tx = threadIdx.x & 31, ty = threadIdx.x >> 5;
#pragma unroll
    for (int p = 0; p < 4; ++p) {
        int kk = ty + p * 8;
        T[tx][kk] = W[(size_t)(k0 + kk) * 768 + n0 + tx];
    }
    __syncthreads();
#pragma unroll
    for (int p = 0; p < 4; ++p) {
        int nn = ty + p * 8;
        Wo[(size_t)(n0 + nn) * 768 + k0 + tx] = f2bf(T[nn][tx]);
    }
}

// ---------------------------------------------------------------------------
// Build transposed hash-projection weight in bf16: hpwT[hc][kk], kk in [0,896)
__global__ __launch_bounds__(256) void build_hpwT(const float* __restrict__ hp,
                                                  short* __restrict__ hpwT) {
    __shared__ float T[32][33];
    int kk0 = blockIdx.x * 32, hc0 = blockIdx.y * 32;
    int h = hc0 >> 6, cb = hc0 & 63;
    int tx = threadIdx.x & 31, ty = threadIdx.x >> 5;
#pragma unroll
    for (int p = 0; p < 4; ++p) {
        int kp = ty + p * 8;
        int gk = kk0 + kp;
        int ks = (gk >= 768) ? gk - 768 : gk;
        float f = hp[((size_t)h * 768 + ks) * 64 + cb + tx];
        T[tx][kp] = (gk >= 768) ? 0.1f * f : f;
    }
    __syncthreads();
#pragma unroll
    for (int p = 0; p < 4; ++p) {
        int cp = ty + p * 8;
        hpwT[(size_t)(hc0 + cp) * 896 + kk0 + tx] = f2bf(T[cp][tx]);
    }
}

// ---------------------------------------------------------------------------
// MFMA bf16 GEMM, m97 structure: linear LDS + global_load_lds(16) with
// XOR source-pre-swizzle; fragment reads apply matching XOR -> conflict-free.
// Tiles BM=128 BN=64 BK=64, 4 waves (2x2), 16x16x32 MFMA.
// mode 0: f32 store (+bias) to outF;  mode 1: QKV scatter bf16 to outB;
// mode 2: gate: g=sigmoid(acc+bias); outB = bf16(g*gctx+(1-g)*ghs)
__global__ __launch_bounds__(256) void gemm_mfma(
    const short* __restrict__ A, const short* __restrict__ A2,
    const short* __restrict__ Bt, const float* __restrict__ bias,
    float* __restrict__ outF, short* __restrict__ outB,
    int N, int K1, int K2, int mode, int nsub,
    const float* __restrict__ gctx, const float* __restrict__ ghs) {
    __shared__ __align__(16) short As[128 * 64];
    __shared__ __align__(16) short Bs[64 * 64];
    const int t = threadIdx.x;
    const int lane = t & 63, wave = t >> 6;
    const int wm = wave >> 1, wn = wave & 1;
    const int l15 = lane & 15, l4 = lane >> 4;
    const int which = blockIdx.x / nsub;
    const int col0 = (blockIdx.x % nsub) * 64;
    const int row0 = blockIdx.y * 128;
    const short* Bp = Bt + (size_t)which * 589824;
    const int K = K1 + K2;
    // source swizzle: lane covers row (chunk*8 + lane>>3), 16B slot (lane&7)
    const int lrow = lane >> 3;
    const int scolS = (((lane & 7) ^ lrow) << 4) >> 1;  // swizzled col in shorts
    v4f acc[4][2];
#pragma unroll
    for (int m = 0; m < 4; ++m)
#pragma unroll
        for (int n = 0; n < 2; ++n) acc[m][n] = (v4f){0.f, 0.f, 0.f, 0.f};

    for (int k0 = 0; k0 < K; k0 += 64) {
        const short* Ap; int ks, strideS;
        if (k0 < K1) { Ap = A;  ks = k0;      strideS = K1; }
        else         { Ap = A2; ks = k0 - K1; strideS = K2; }
#pragma unroll
        for (int qq = 0; qq < 4; ++qq) {
            int c = wave * 4 + qq;                       // A chunk: rows 8c..8c+7
            const short* g = Ap + (size_t)(row0 + c * 8 + lrow) * strideS + ks + scolS;
            load_lds16(g, (char*)As + c * 1024);
        }
#pragma unroll
        for (int qq = 0; qq < 2; ++qq) {
            int c = wave * 2 + qq;                       // B chunk
            const short* g = Bp + (size_t)(col0 + c * 8 + lrow) * K + k0 + scolS;
            load_lds16(g, (char*)Bs + c * 1024);
        }
        __syncthreads();   // compiler drains vmcnt(0) -> DMA complete
#pragma unroll
        for (int kk = 0; kk < 2; ++kk) {
            v8s a[4], b[2];
#pragma unroll
            for (int m = 0; m < 4; ++m) {
                int row = wm * 64 + m * 16 + l15;
                int byte = (row * 128 + kk * 64 + l4 * 16) ^ ((row & 7) << 4);
                a[m] = *(const v8s*)((const char*)As + byte);
            }
#pragma unroll
            for (int n = 0; n < 2; ++n) {
                int row = wn * 32 + n * 16 + l15;
                int byte = (row * 128 + kk * 64 + l4 * 16) ^ ((row & 7) << 4);
                b[n] = *(const v8s*)((const char*)Bs + byte);
            }
#pragma unroll
            for (int m = 0; m < 4; ++m) {
                acc[m][0] = __builtin_amdgcn_mfma_f32_16x16x32_bf16(a[m], b[0], acc[m][0], 0, 0, 0);
                acc[m][1] = __builtin_amdgcn_mfma_f32_16x16x32_bf16(a[m], b[1], acc[m][1], 0, 0, 0);
            }
        }
        __syncthreads();
    }
#pragma unroll
    for (int m = 0; m < 4; ++m) {
#pragma unroll
        for (int n = 0; n < 2; ++n) {
            int gr0 = row0 + (wm * 4 + m) * 16 + l4 * 4;
            int gc = col0 + (wn * 2 + n) * 16 + l15;
#pragma unroll
            for (int i = 0; i < 4; ++i) {
                int gr = gr0 + i;
                float c = acc[m][n][i];
                if (mode == 0) {
                    if (bias) c += bias[gc];
                    outF[(size_t)gr * N + gc] = c;
                } else if (mode == 1) {
                    int bb = gr >> 11, s = gr & 2047;
                    int h = gc >> 6, hd = gc & 63;
                    outB[(size_t)which * 3145728 +
                         (((size_t)(bb * HH + h)) * SS + s) * HDIM + hd] = f2bf(c);
                } else {
                    c += bias[gc];
                    float g = 1.f / (1.f + __expf(-c));
                    size_t off = (size_t)gr * N + gc;
                    outB[off] = f2bf(g * gctx[off] + (1.f - g) * ghs[off]);
                }
            }
        }
    }
}

// ---------------------------------------------------------------------------
// Pack sign bits of proj[4096][512] into codes[4096][8] u64 via wave ballot.
// Block 0 also zero-inits the chunkmask bitmap.
__global__ __launch_bounds__(512) void pack_codes(const float* __restrict__ proj,
                                                  unsigned long long* __restrict__ codes,
                                                  unsigned int* __restrict__ cmask) {
    int row = blockIdx.x, t = threadIdx.x;
    if (row == 0 && t < 64) cmask[t] = 0u;
    float v = proj[(size_t)row * 512 + t];
    unsigned long long bal = __ballot(v > 0.f);
    if ((t & 63) == 0) codes[(size_t)row * NWORDS + (t >> 6)] = bal;
}

// ---------------------------------------------------------------------------
// LSH keep masks: one (qchunk, kchunk, b) tile per block, 2048 blocks.
__global__ __launch_bounds__(256) void mask_kernel(
    const unsigned long long* __restrict__ codes, const int* __restrict__ mask,
    unsigned long long* __restrict__ keepArr, unsigned int* __restrict__ chunkmask) {
    __shared__ unsigned long long ckS[64][NWORDS];
    __shared__ int mskS[64];
    const int t = threadIdx.x;
    const int r = t >> 2, tx = t & 3;
    const int qc = blockIdx.x, kc = blockIdx.y, b = blockIdx.z;
    const int q0 = qc << 6, k0 = kc << 6;

#pragma unroll
    for (int p = 0; p < 2; ++p) {
        int idx = t + (p << 8);
        int jr = idx >> 3, ww = idx & 7;
        ckS[jr][ww ^ (jr >> 4)] =
            codes[((size_t)(b * SS + k0 + jr)) * NWORDS + ww];
    }
    if (t < 64) mskS[t] = mask[b * SS + k0 + t];
    unsigned long long cq[NWORDS];
    {
        const unsigned long long* cp = codes + ((size_t)(b * SS + q0 + r)) * NWORDS;
#pragma unroll
        for (int w = 0; w < NWORDS; ++w) cq[w] = cp[w];
    }
    __syncthreads();

    unsigned long long k64 = 0;
#pragma unroll
    for (int j16 = 0; j16 < 16; ++j16) {
        int j = (tx << 4) + j16;
        int ham = 0;
#pragma unroll
        for (int w = 0; w < NWORDS; ++w)
            ham += __popcll(cq[w] ^ ckS[j][w ^ tx]);
        if (ham <= HAM_MAX && mskS[j]) k64 |= 1ull << j;
    }
    k64 |= __shfl_xor(k64, 1, 4);
    k64 |= __shfl_xor(k64, 2, 4);
    if (tx == 0) keepArr[((size_t)(b * SS + q0 + r)) * 32 + kc] = k64;
    if (__syncthreads_or(k64 != 0) && t == 0)
        atomicOr(&chunkmask[b * 32 + qc], 1u << kc);
}

// ---------------------------------------------------------------------------
// MFMA flash attention over active chunks only. bf16 Q/K/V.
// 4 waves; wave w owns score/output rows w*16..w*16+15 (same C-layout for
// QK^T and PV -> softmax stats stay lane-local: row = l4*4+i).
__global__ __launch_bounds__(256) void attn_kernel(
    const short* __restrict__ qm, const short* __restrict__ km,
    const short* __restrict__ vm, const unsigned long long* __restrict__ keepArr,
    const unsigned int* __restrict__ chunkmask, float* __restrict__ ctx,
    short* __restrict__ ctxbf) {
    __shared__ __align__(16) short Qs[64][72];
    __shared__ __align__(16) short Ks[64][72];
    __shared__ __align__(16) short VT[64][72];   // V transposed: [dim][key]
    __shared__ __align__(16) short Ps[64][72];
    __shared__ unsigned long long keepS[64];
    const int t = threadIdx.x;
    const int lane = t & 63, wave = t >> 6;
    const int l15 = lane & 15, l4 = lane >> 4;
    const int q0 = blockIdx.x << 6;
    const int bh = blockIdx.y;
    const int b = bh / HH, h = bh % HH;

    {   // stage Q (direct bf16 copy)
        int r = t >> 2, seg = t & 3;
        const short* g = qm + ((size_t)bh * SS + q0 + r) * HDIM + seg * 16;
        *(int4*)&Qs[r][seg * 16] = *(const int4*)g;
        *(int4*)&Qs[r][seg * 16 + 8] = *(const int4*)(g + 8);
    }
    unsigned int cm = chunkmask[b * 32 + blockIdx.x];
    float mrun[4], lrun[4];
    v4f oacc[4];
#pragma unroll
    for (int i = 0; i < 4; ++i) { mrun[i] = -1e30f; lrun[i] = 0.f; }
#pragma unroll
    for (int n = 0; n < 4; ++n) oacc[n] = (v4f){0.f, 0.f, 0.f, 0.f};

    while (cm) {
        int kc = __ffs(cm) - 1;
        cm &= cm - 1;
        __syncthreads();   // prev chunk's reads done (1st iter: nothing)
        if (t < 64) keepS[t] = keepArr[((size_t)(b * SS + q0 + t)) * 32 + kc];
        {   // stage K rows + V transposed
            int key = t >> 2, seg = t & 3;
            const short* gk = km + ((size_t)bh * SS + (kc << 6) + key) * HDIM + seg * 16;
            *(int4*)&Ks[key][seg * 16] = *(const int4*)gk;
            *(int4*)&Ks[key][seg * 16 + 8] = *(const int4*)(gk + 8);
            const short* gv = vm + ((size_t)bh * SS + (kc << 6) + key) * HDIM + seg * 16;
            int4 v0 = *(const int4*)gv, v1 = *(const int4*)(gv + 8);
            const short* s0 = (const short*)&v0;
            const short* s1 = (const short*)&v1;
#pragma unroll
            for (int e = 0; e < 8; ++e) VT[seg * 16 + e][key] = s0[e];
#pragma unroll
            for (int e = 0; e < 8; ++e) VT[seg * 16 + 8 + e][key] = s1[e];
        }
        __syncthreads();

        // QK^T: S[64 rows][64 keys], wave computes 16 rows x 64 keys
        v8s qa0 = *(const v8s*)&Qs[wave * 16 + l15][l4 * 8];
        v8s qa1 = *(const v8s*)&Qs[wave * 16 + l15][32 + l4 * 8];
        v4f sacc[4];
#pragma unroll
        for (int n = 0; n < 4; ++n) sacc[n] = (v4f){0.f, 0.f, 0.f, 0.f};
#pragma unroll
        for (int n = 0; n < 4; ++n) {
            v8s kb0 = *(const v8s*)&Ks[n * 16 + l15][l4 * 8];
            v8s kb1 = *(const v8s*)&Ks[n * 16 + l15][32 + l4 * 8];
            sacc[n] = __builtin_amdgcn_mfma_f32_16x16x32_bf16(qa0, kb0, sacc[n], 0, 0, 0);
            sacc[n] = __builtin_amdgcn_mfma_f32_16x16x32_bf16(qa1, kb1, sacc[n], 0, 0, 0);
        }
        // online softmax; row r = wave*16 + l4*4 + i lives in component i
        unsigned long long kp[4];
#pragma unroll
        for (int i = 0; i < 4; ++i) kp[i] = keepS[wave * 16 + l4 * 4 + i];
        float pe[4][4], mloc[4];
#pragma unroll
        for (int i = 0; i < 4; ++i) mloc[i] = -1e30f;
#pragma unroll
        for (int n = 0; n < 4; ++n)
#pragma unroll
            for (int i = 0; i < 4; ++i) {
                bool keep = (kp[i] >> (n * 16 + l15)) & 1;
                float sv = keep ? sacc[n][i] * 0.125f : -1e30f;
                pe[n][i] = sv;
                mloc[i] = fmaxf(mloc[i], sv);
            }
#pragma unroll
        for (int i = 0; i < 4; ++i) {
            mloc[i] = fmaxf(mloc[i], __shfl_xor(mloc[i], 1, 16));
            mloc[i] = fmaxf(mloc[i], __shfl_xor(mloc[i], 2, 16));
            mloc[i] = fmaxf(mloc[i], __shfl_xor(mloc[i], 4, 16));
            mloc[i] = fmaxf(mloc[i], __shfl_xor(mloc[i], 8, 16));
        }
        float psum[4] = {0.f, 0.f, 0.f, 0.f};
#pragma unroll
        for (int n = 0; n < 4; ++n)
#pragma unroll
            for (int i = 0; i < 4; ++i) {
                bool keep = pe[n][i] > -1e29f;
                float mnew = fmaxf(mrun[i], mloc[i]);
                float p = keep ? __expf(pe[n][i] - mnew) : 0.f;
                pe[n][i] = p;
                psum[i] += p;
            }
#pragma unroll
        for (int i = 0; i < 4; ++i) {
            psum[i] += __shfl_xor(psum[i], 1, 16);
            psum[i] += __shfl_xor(psum[i], 2, 16);
            psum[i] += __shfl_xor(psum[i], 4, 16);
            psum[i] += __shfl_xor(psum[i], 8, 16);
            float mnew = fmaxf(mrun[i], mloc[i]);
            float scale = __expf(mrun[i] - mnew);
            lrun[i] = lrun[i] * scale + psum[i];
            mrun[i] = mnew;
#pragma unroll
            for (int n = 0; n < 4; ++n) oacc[n][i] *= scale;
        }
        // P -> bf16 LDS (C-layout write)
#pragma unroll
        for (int n = 0; n < 4; ++n)
#pragma unroll
            for (int i = 0; i < 4; ++i)
                Ps[wave * 16 + l4 * 4 + i][n * 16 + l15] = f2bf(pe[n][i]);
        __syncthreads();

        // PV: out += P[16 rows x 64 keys] * V[64 keys x 64 dims]
        v8s pa0 = *(const v8s*)&Ps[wave * 16 + l15][l4 * 8];
        v8s pa1 = *(const v8s*)&Ps[wave * 16 + l15][32 + l4 * 8];
#pragma unroll
        for (int n = 0; n < 4; ++n) {
            v8s vb0 = *(const v8s*)&VT[n * 16 + l15][l4 * 8];
            v8s vb1 = *(const v8s*)&VT[n * 16 + l15][32 + l4 * 8];
            oacc[n] = __builtin_amdgcn_mfma_f32_16x16x32_bf16(pa0, vb0, oacc[n], 0, 0, 0);
            oacc[n] = __builtin_amdgcn_mfma_f32_16x16x32_bf16(pa1, vb1, oacc[n], 0, 0, 0);
        }
    }
    float invl[4];
#pragma unroll
    for (int i = 0; i < 4; ++i) invl[i] = lrun[i] > 0.f ? 1.f / lrun[i] : 0.f;
#pragma unroll
    for (int n = 0; n < 4; ++n)
#pragma unroll
        for (int i = 0; i < 4; ++i) {
            int r = wave * 16 + l4 * 4 + i;
            size_t off = ((size_t)b * SS + q0 + r) * DD + h * HDIM + n * 16 + l15;
            float val = oacc[n][i] * invl[i];
            ctx[off] = val;
            ctxbf[off] = f2bf(val);
        }
}

// ---------------------------------------------------------------------------
extern "C" void kernel_launch(void* const* d_in, const int* in_sizes, int n_in,
                              void* d_out, int out_size, void* d_ws, size_t ws_size,
                              hipStream_t stream) {
    const float* hs = (const float*)d_in[0];
    const float* tf = (const float*)d_in[1];
    const float* Wq = (const float*)d_in[2];
    const float* Wk = (const float*)d_in[3];
    const float* Wv = (const float*)d_in[4];
    const float* Wo = (const float*)d_in[5];
    const float* bo = (const float*)d_in[6];
    const float* Wg = (const float*)d_in[7];
    const float* bg = (const float*)d_in[8];
    const float* hp = (const float*)d_in[9];
    const float* tb = (const float*)d_in[10];
    const int* msk  = (const int*)d_in[11];
    float* out = (float*)d_out;

    char* w = (char*)d_ws;
    short* qkvbf  = (short*)(w + OFF_QBF);
    float* ctx    = (float*)(w + OFF_CTX);
    short* hsbf   = (short*)(w + OFF_HSBF);
    short* tfbf   = (short*)(w + OFF_TFBF);
    short* ctxbf  = (short*)(w + OFF_CTXBF);
    short* ctx2bf = (short*)(w + OFF_CTX2BF);
    short* wtqkv  = (short*)(w + OFF_WTQKV);
    short* wgT    = (short*)(w + OFF_WGT);
    short* woT    = (short*)(w + OFF_WOT);
    short* hpwT   = (short*)(w + OFF_HPWT);
    float* proj   = (float*)(w + OFF_PROJ);
    unsigned long long* codes = (unsigned long long*)(w + OFF_CODES);
    unsigned long long* keepA = (unsigned long long*)(w + OFF_KEEP);
    unsigned int* cmask = (unsigned int*)(w + OFF_CMASK);

    // 1. activations -> bf16
    conv_act<<<dim3((3145728 / 8 + 524288 / 8 + 255) / 256), 256, 0, stream>>>(
        hs, 3145728 / 8, tf, 524288 / 8, hsbf, tfbf);
    // 2-4. weights -> transposed bf16
    tconv3<<<dim3(24, 24, 3), 256, 0, stream>>>(Wq, Wk, Wv, wtqkv);
    tconvW<<<dim3(24, 28), 256, 0, stream>>>(Wg, wgT, 896, 768);
    tconvW<<<dim3(24, 24), 256, 0, stream>>>(Wo, woT, 768, 768);
    build_hpwT<<<dim3(28, 16), 256, 0, stream>>>(hp, hpwT);
    // 5. fused QKV -> bf16 [B,H,S,HD] x3
    gemm_mfma<<<dim3(36, 32), 256, 0, stream>>>(
        hsbf, nullptr, wtqkv, nullptr, nullptr, qkvbf, 768, 768, 0, 1, 12, nullptr, nullptr);
    // 6. LSH projection -> proj f32
    gemm_mfma<<<dim3(8, 32), 256, 0, stream>>>(
        hsbf, tfbf, hpwT, tb, proj, nullptr, 512, 768, 128, 0, 8, nullptr, nullptr);
    // 7-9. codes (+cmask zero), masks, attention
    pack_codes<<<4096, 512, 0, stream>>>(proj, codes, cmask);
    mask_kernel<<<dim3(32, 32, 2), 256, 0, stream>>>(codes, msk, keepA, cmask);
    attn_kernel<<<dim3(32, 24), 256, 0, stream>>>(
        qkvbf, qkvbf + 3145728, qkvbf + 2 * 3145728, keepA, cmask, ctx, ctxbf);
    // 10. gate GEMM + sigmoid-blend epilogue -> ctx2 bf16
    gemm_mfma<<<dim3(12, 32), 256, 0, stream>>>(
        ctxbf, tfbf, wgT, bg, nullptr, ctx2bf, 768, 768, 128, 2, 12, ctx, hs);
    // 11. output projection -> d_out f32
    gemm_mfma<<<dim3(12, 32), 256, 0, stream>>>(
        ctx2bf, nullptr, woT, bo, out, nullptr, 768, 768, 0, 0, 12, nullptr, nullptr);
}